// Round 1
// baseline (484.279 us; speedup 1.0000x reference)
//
#include <hip/hip_runtime.h>
#include <cstdint>
#include <cstddef>

typedef unsigned short u16;
typedef short bf16x8 __attribute__((ext_vector_type(8)));
typedef unsigned short u16x4 __attribute__((ext_vector_type(4)));
typedef float f32x4 __attribute__((ext_vector_type(4)));
typedef float f32x2 __attribute__((ext_vector_type(2)));

#define EPSN 1e-12f

__device__ __forceinline__ u16 f2bf(float f) {
  uint32_t u = __builtin_bit_cast(uint32_t, f);
  u += 0x7FFFu + ((u >> 16) & 1u);
  return (u16)(u >> 16);
}
__device__ __forceinline__ float bf2f(u16 h) {
  uint32_t u = ((uint32_t)h) << 16;
  return __builtin_bit_cast(float, u);
}

// ---------------------------------------------------------------------------
// Transpose-convert Wqkv (768x2304 f32) -> Wt (2304x768 bf16)  (B^T layout)
// ---------------------------------------------------------------------------
__global__ __launch_bounds__(256)
void k_wt(const float* __restrict__ W, u16* __restrict__ Wt) {
  __shared__ float tile[32][33];
  const int j0 = blockIdx.x * 32;   // col of W (0..2303)
  const int k0 = blockIdx.y * 32;   // row of W (0..767)
  const int tx = threadIdx.x & 31;
  const int ty = threadIdx.x >> 5;  // 0..7
#pragma unroll
  for (int r = 0; r < 4; r++)
    tile[ty + r * 8][tx] = W[(size_t)(k0 + ty + r * 8) * 2304 + j0 + tx];
  __syncthreads();
#pragma unroll
  for (int r = 0; r < 4; r++)
    Wt[(size_t)(j0 + ty + r * 8) * 768 + k0 + tx] = f2bf(tile[tx][ty + r * 8]);
}

// ---------------------------------------------------------------------------
// MFMA GEMM: C[M x Nn] = A[M x K] * B[K x Nn], B given transposed (Bt[Nn][K]).
// 128x128 tile, BK=32, 4 waves (2x2), each wave 64x64 out (4x4 frags 16x16x32).
// AF32: A is fp32 (converted to bf16 during LDS staging), else A is bf16.
// OUTF32B: fp32 output + bias, else bf16 output.
// ---------------------------------------------------------------------------
template <int AF32, int OUTF32B>
__global__ __launch_bounds__(256, 2)
void k_gemm(const void* __restrict__ Ap, const u16* __restrict__ Btp,
            void* __restrict__ Cp, const float* __restrict__ bias,
            int K, int lda, int ldb, int ldc,
            int aColOff, long bBatchStride, int rowsPerBatch) {
  __shared__ u16 As[128][40];  // pad to 40 elems (80B row) -> ~2-way banks, 16B aligned
  __shared__ u16 Bs[128][40];
  const int tid = threadIdx.x;
  const int lane = tid & 63;
  const int wid = tid >> 6;
  const int wr = wid >> 1, wc = wid & 1;
  const int fm = lane & 15, kg = lane >> 4;
  const int m0 = blockIdx.y * 128;
  const int n0 = blockIdx.x * 128;

  const u16* Bt = Btp + (bBatchStride ? (long)(m0 / rowsPerBatch) * bBatchStride : 0);

  const int srow = tid >> 1;         // 0..127
  const int scol = (tid & 1) * 16;   // 0 or 16
  const size_t aBase = (size_t)(m0 + srow) * lda + aColOff + scol;
  const size_t bBase = (size_t)(n0 + srow) * ldb + scol;
  const float* Af = (const float*)Ap;
  const u16* Ah = (const u16*)Ap;

  f32x4 a0, a1, a2, a3;
  bf16x8 ah0, ah1, bh0, bh1;

  auto LOAD = [&](int k0) {
    if constexpr (AF32) {
      const float* p = Af + aBase + k0;
      a0 = *(const f32x4*)(p);
      a1 = *(const f32x4*)(p + 4);
      a2 = *(const f32x4*)(p + 8);
      a3 = *(const f32x4*)(p + 12);
    } else {
      const u16* p = Ah + aBase + k0;
      ah0 = *(const bf16x8*)(p);
      ah1 = *(const bf16x8*)(p + 8);
    }
    const u16* q = Bt + bBase + k0;
    bh0 = *(const bf16x8*)(q);
    bh1 = *(const bf16x8*)(q + 8);
  };
  auto STORE = [&]() {
    if constexpr (AF32) {
      float s[16] = {a0[0], a0[1], a0[2], a0[3], a1[0], a1[1], a1[2], a1[3],
                     a2[0], a2[1], a2[2], a2[3], a3[0], a3[1], a3[2], a3[3]};
      bf16x8 t0, t1;
#pragma unroll
      for (int e = 0; e < 8; e++) {
        t0[e] = (short)f2bf(s[e]);
        t1[e] = (short)f2bf(s[8 + e]);
      }
      *(bf16x8*)&As[srow][scol] = t0;
      *(bf16x8*)&As[srow][scol + 8] = t1;
    } else {
      *(bf16x8*)&As[srow][scol] = ah0;
      *(bf16x8*)&As[srow][scol + 8] = ah1;
    }
    *(bf16x8*)&Bs[srow][scol] = bh0;
    *(bf16x8*)&Bs[srow][scol + 8] = bh1;
  };

  f32x4 acc[4][4] = {};
  LOAD(0);
  for (int k0 = 0; k0 < K; k0 += 32) {
    __syncthreads();
    STORE();
    if (k0 + 32 < K) LOAD(k0 + 32);
    __syncthreads();
    bf16x8 af[4], bfr[4];
#pragma unroll
    for (int i = 0; i < 4; i++)
      af[i] = *(const bf16x8*)&As[wr * 64 + i * 16 + fm][kg * 8];
#pragma unroll
    for (int j = 0; j < 4; j++)
      bfr[j] = *(const bf16x8*)&Bs[wc * 64 + j * 16 + fm][kg * 8];
#pragma unroll
    for (int i = 0; i < 4; i++)
#pragma unroll
      for (int j = 0; j < 4; j++)
        acc[i][j] = __builtin_amdgcn_mfma_f32_16x16x32_bf16(af[i], bfr[j], acc[i][j], 0, 0, 0);
  }

  if constexpr (OUTF32B) {
    float* C = (float*)Cp;
#pragma unroll
    for (int j = 0; j < 4; j++) {
      const int col = n0 + wc * 64 + j * 16 + fm;
      const float bj = bias[col];
#pragma unroll
      for (int i = 0; i < 4; i++) {
        const int r0 = m0 + wr * 64 + i * 16 + kg * 4;
#pragma unroll
        for (int r = 0; r < 4; r++)
          C[(size_t)(r0 + r) * ldc + col] = acc[i][j][r] + bj;
      }
    }
  } else {
    u16* C = (u16*)Cp;
#pragma unroll
    for (int j = 0; j < 4; j++) {
      const int col = n0 + wc * 64 + j * 16 + fm;
#pragma unroll
      for (int i = 0; i < 4; i++) {
        const int r0 = m0 + wr * 64 + i * 16 + kg * 4;
#pragma unroll
        for (int r = 0; r < 4; r++)
          C[(size_t)(r0 + r) * ldc + col] = f2bf(acc[i][j][r]);
      }
    }
  }
}

// ---------------------------------------------------------------------------
// Gram: per (b,h, split s): partial G[c,d] = sum_t Q[t][c] K[t][d] over 512 t,
// plus partial squared column norms of Q and K.
// ---------------------------------------------------------------------------
__global__ __launch_bounds__(256)
void k_gram(const u16* __restrict__ C1, float* __restrict__ Gpart,
            float* __restrict__ NqP, float* __restrict__ NkP) {
  const int s = blockIdx.x, h = blockIdx.y, b = blockIdx.z;
  const int tid = threadIdx.x;
  __shared__ float Qs[32][96];
  __shared__ float Ks[32][96];
  const int cg = tid >> 4, dg = tid & 15;
  const int c0 = cg * 6, d0 = dg * 6;
  float accg[6][6] = {};
  float accq[6] = {}, acck[6] = {};
  const size_t qbase = ((size_t)b * 4096) * 2304 + (size_t)h * 96;
  const size_t kbase = qbase + 768;
  const int t0 = s * 512;

  for (int tile = 0; tile < 16; tile++) {
    const int ts = t0 + tile * 32;
    __syncthreads();
#pragma unroll
    for (int it = 0; it < 3; it++) {
      const int idx = tid + it * 256;  // 0..767 (short4 chunks: 32 t x 24)
      const int tt = idx / 24;
      const int cc = (idx % 24) * 4;
      const size_t roff = (size_t)(ts + tt) * 2304 + cc;
      u16x4 vq = *(const u16x4*)(C1 + qbase + roff);
      u16x4 vk = *(const u16x4*)(C1 + kbase + roff);
      f32x4 fq, fk;
#pragma unroll
      for (int e = 0; e < 4; e++) {
        fq[e] = bf2f(vq[e]);
        fk[e] = bf2f(vk[e]);
      }
      *(f32x4*)&Qs[tt][cc] = fq;
      *(f32x4*)&Ks[tt][cc] = fk;
    }
    __syncthreads();
    for (int tt = 0; tt < 32; tt++) {
      f32x2 qa = *(const f32x2*)&Qs[tt][c0];
      f32x2 qb = *(const f32x2*)&Qs[tt][c0 + 2];
      f32x2 qc = *(const f32x2*)&Qs[tt][c0 + 4];
      f32x2 ka = *(const f32x2*)&Ks[tt][d0];
      f32x2 kb = *(const f32x2*)&Ks[tt][d0 + 2];
      f32x2 kc = *(const f32x2*)&Ks[tt][d0 + 4];
      float q[6] = {qa[0], qa[1], qb[0], qb[1], qc[0], qc[1]};
      float k[6] = {ka[0], ka[1], kb[0], kb[1], kc[0], kc[1]};
#pragma unroll
      for (int i = 0; i < 6; i++)
#pragma unroll
        for (int j = 0; j < 6; j++) accg[i][j] += q[i] * k[j];
      if (dg == 0) {
#pragma unroll
        for (int i = 0; i < 6; i++) accq[i] += q[i] * q[i];
      }
      if (cg == 0) {
#pragma unroll
        for (int j = 0; j < 6; j++) acck[j] += k[j] * k[j];
      }
    }
  }
  const int blk = (b * 8 + h) * 8 + s;
  float* G = Gpart + (size_t)blk * 9216;
#pragma unroll
  for (int i = 0; i < 6; i++)
#pragma unroll
    for (int j2 = 0; j2 < 3; j2++) {
      f32x2 v;
      v[0] = accg[i][j2 * 2];
      v[1] = accg[i][j2 * 2 + 1];
      *(f32x2*)&G[(c0 + i) * 96 + d0 + j2 * 2] = v;
    }
  if (dg == 0) {
#pragma unroll
    for (int i = 0; i < 6; i++) NqP[(size_t)blk * 96 + c0 + i] = accq[i];
  }
  if (cg == 0) {
#pragma unroll
    for (int j = 0; j < 6; j++) NkP[(size_t)blk * 96 + d0 + j] = acck[j];
  }
}

// ---------------------------------------------------------------------------
// Reduce partials, apply normalization + temperature, softmax rows -> Aattn
// ---------------------------------------------------------------------------
__global__ __launch_bounds__(128)
void k_softmax(const float* __restrict__ Gpart, const float* __restrict__ NqP,
               const float* __restrict__ NkP, const float* __restrict__ temperature,
               float* __restrict__ Aattn) {
  const int h = blockIdx.x, b = blockIdx.y;
  const int bh = b * 8 + h;
  const int tid = threadIdx.x;
  __shared__ float Gs[9216];
  __shared__ float inq[96], ink[96];
  if (tid < 96) {
    float sq = 0.f, sk = 0.f;
    for (int s = 0; s < 8; s++) {
      sq += NqP[(size_t)(bh * 8 + s) * 96 + tid];
      sk += NkP[(size_t)(bh * 8 + s) * 96 + tid];
    }
    float nq = sqrtf(sq); if (nq < EPSN) nq = EPSN;
    float nk = sqrtf(sk); if (nk < EPSN) nk = EPSN;
    inq[tid] = 1.0f / nq;
    ink[tid] = 1.0f / nk;
  }
  for (int idx = tid; idx < 9216; idx += 128) {
    float g = 0.f;
    for (int s = 0; s < 8; s++) g += Gpart[(size_t)(bh * 8 + s) * 9216 + idx];
    Gs[idx] = g;
  }
  __syncthreads();
  const float tmp = temperature[h];
  if (tid < 96) {
    const int c = tid;
    const float qn = inq[c] * tmp;
    float sv[96];
    float m = -1e30f;
#pragma unroll
    for (int d = 0; d < 96; d++) {
      float sval = Gs[c * 96 + d] * qn * ink[d];
      sv[d] = sval;
      m = fmaxf(m, sval);
    }
    float sum = 0.f;
#pragma unroll
    for (int d = 0; d < 96; d++) {
      float e = __expf(sv[d] - m);
      sv[d] = e;
      sum += e;
    }
    const float inv = 1.0f / sum;
    float* dst = Aattn + (size_t)bh * 9216 + (size_t)c * 96;
#pragma unroll
    for (int d = 0; d < 96; d++) dst[d] = sv[d] * inv;
  }
}

// ---------------------------------------------------------------------------
// Weff_t[b][j][d] = sum_c A[b, h(d), c, dc(d)] * Wproj[h*96+c][j]   (bf16 out)
// block = (jt, h, b): 128 j x 96 dc tile.
// ---------------------------------------------------------------------------
__global__ __launch_bounds__(256)
void k_weff(const float* __restrict__ Aattn, const float* __restrict__ Wproj,
            u16* __restrict__ Weff) {
  const int jt = blockIdx.x, h = blockIdx.y, b = blockIdx.z;
  const int bh = b * 8 + h;
  __shared__ float As2[9216];
  const int tid = threadIdx.x;
  for (int idx = tid; idx < 9216; idx += 256)
    As2[idx] = Aattn[(size_t)bh * 9216 + idx];
  __syncthreads();
  const int jloc = tid & 127;
  const int half = tid >> 7;  // 0/1 -> dc range half*48
  const int j = jt * 128 + jloc;
  float acc[48] = {};
  for (int c = 0; c < 96; c++) {
    const float w = Wproj[(size_t)(h * 96 + c) * 768 + j];
    const f32x4* ar = (const f32x4*)&As2[c * 96 + half * 48];
#pragma unroll
    for (int v4 = 0; v4 < 12; v4++) {
      f32x4 a = ar[v4];
      acc[v4 * 4 + 0] += w * a[0];
      acc[v4 * 4 + 1] += w * a[1];
      acc[v4 * 4 + 2] += w * a[2];
      acc[v4 * 4 + 3] += w * a[3];
    }
  }
  u16* dst = Weff + ((size_t)b * 768 + j) * 768 + h * 96 + half * 48;
#pragma unroll
  for (int v4 = 0; v4 < 12; v4++) {
    u16x4 o;
    o[0] = f2bf(acc[v4 * 4 + 0]);
    o[1] = f2bf(acc[v4 * 4 + 1]);
    o[2] = f2bf(acc[v4 * 4 + 2]);
    o[3] = f2bf(acc[v4 * 4 + 3]);
    *(u16x4*)(dst + v4 * 4) = o;
  }
}

// ---------------------------------------------------------------------------
extern "C" void kernel_launch(void* const* d_in, const int* in_sizes, int n_in,
                              void* d_out, int out_size, void* d_ws, size_t ws_size,
                              hipStream_t stream) {
  const float* x = (const float*)d_in[0];        // (8,4096,768)
  const float* Wqkv = (const float*)d_in[1];     // (768,2304)
  const float* temp = (const float*)d_in[2];     // (8,1,1)
  const float* Wproj = (const float*)d_in[3];    // (768,768)
  const float* bproj = (const float*)d_in[4];    // (768,)
  float* out = (float*)d_out;                    // (8,4096,768) f32

  char* ws = (char*)d_ws;
  u16* C1 = (u16*)ws;                            // qkv bf16: 32768x2304 = 150,994,944 B
  u16* Wt = (u16*)(ws + 150994944);              // Wqkv^T bf16: 3,538,944 B
  float* Gpart = (float*)(ws + 154533888);       // 512 x 96 x 96 f32 = 18,874,368 B
  float* NqP = (float*)(ws + 173408256);         // 512 x 96 f32
  float* NkP = (float*)(ws + 173604864);         // 512 x 96 f32
  float* Aattn = (float*)(ws + 173801472);       // 64 x 96 x 96 f32
  u16* Weff = (u16*)(ws + 176160768);            // 8 x 768 x 768 bf16 = 9,437,184 B
  // total ws use: 185,597,952 B

  // 1. Wqkv -> transposed bf16
  k_wt<<<dim3(72, 24), 256, 0, stream>>>(Wqkv, Wt);
  // 2. qkv = x @ Wqkv  (bf16 MFMA, bf16 out)
  k_gemm<1, 0><<<dim3(18, 256), 256, 0, stream>>>(
      (const void*)x, Wt, (void*)C1, nullptr, 768, 768, 768, 2304, 0, 0L, 1);
  // 3. per (b,h): partial Gram + norms over N
  k_gram<<<dim3(8, 8, 8), 256, 0, stream>>>(C1, Gpart, NqP, NkP);
  // 4. reduce + normalize + softmax -> Aattn
  k_softmax<<<dim3(8, 8), 128, 0, stream>>>(Gpart, NqP, NkP, temp, Aattn);
  // 5. Weff[b] = blockdiag(A)^T @ Wproj  (stored transposed, bf16)
  k_weff<<<dim3(6, 8, 8), 256, 0, stream>>>(Aattn, Wproj, Weff);
  // 6. out = V @ Weff[b] + bproj  (f32 out)
  k_gemm<0, 1><<<dim3(6, 256), 256, 0, stream>>>(
      (const void*)C1, Weff, (void*)out, bproj, 768, 2304, 768, 768, 1536, 589824L, 4096);
}

// Round 2
// 387.027 us; speedup vs baseline: 1.2513x; 1.2513x over previous
//
#include <hip/hip_runtime.h>
#include <cstdint>
#include <cstddef>

typedef unsigned short u16;
typedef short bf16x8 __attribute__((ext_vector_type(8)));
typedef unsigned short u16x4 __attribute__((ext_vector_type(4)));
typedef unsigned short u16x8 __attribute__((ext_vector_type(8)));
typedef float f32x4 __attribute__((ext_vector_type(4)));
typedef float f32x2 __attribute__((ext_vector_type(2)));

#define EPSN 1e-12f

__device__ __forceinline__ u16 f2bf(float f) {
  uint32_t u = __builtin_bit_cast(uint32_t, f);
  u += 0x7FFFu + ((u >> 16) & 1u);
  return (u16)(u >> 16);
}
__device__ __forceinline__ float bf2f(u16 h) {
  uint32_t u = ((uint32_t)h) << 16;
  return __builtin_bit_cast(float, u);
}

__device__ __forceinline__ void gll16(const u16* g, u16* l) {
  __builtin_amdgcn_global_load_lds(
      (const __attribute__((address_space(1))) void*)g,
      (__attribute__((address_space(3))) void*)l, 16, 0, 0);
}

// ---------------------------------------------------------------------------
// Convert x f32 -> bf16 (vectorized 8/thread)
// ---------------------------------------------------------------------------
__global__ __launch_bounds__(256)
void k_cvt(const float* __restrict__ x, u16* __restrict__ Xh, int n8) {
  int i = blockIdx.x * blockDim.x + threadIdx.x;
  const int stride = gridDim.x * blockDim.x;
  for (; i < n8; i += stride) {
    f32x4 a = ((const f32x4*)x)[2 * (size_t)i];
    f32x4 b = ((const f32x4*)x)[2 * (size_t)i + 1];
    u16x8 o;
#pragma unroll
    for (int e = 0; e < 4; e++) {
      o[e] = f2bf(a[e]);
      o[4 + e] = f2bf(b[e]);
    }
    *(u16x8*)(Xh + (size_t)i * 8) = o;
  }
}

// ---------------------------------------------------------------------------
// Wqkv (768x2304 f32): cols [0,1536) -> Wt transposed bf16 (1536x768);
//                      cols [1536,2304) -> Wvh row-major bf16 (768x768)
// ---------------------------------------------------------------------------
__global__ __launch_bounds__(256)
void k_wt(const float* __restrict__ W, u16* __restrict__ Wt, u16* __restrict__ Wvh) {
  __shared__ float tile[32][33];
  const int j0 = blockIdx.x * 32;   // col of W (0..2303)
  const int k0 = blockIdx.y * 32;   // row of W (0..767)
  const int tx = threadIdx.x & 31;
  const int ty = threadIdx.x >> 5;  // 0..7
#pragma unroll
  for (int r = 0; r < 4; r++) {
    float v = W[(size_t)(k0 + ty + r * 8) * 2304 + j0 + tx];
    tile[ty + r * 8][tx] = v;
    if (j0 >= 1536)
      Wvh[(size_t)(k0 + ty + r * 8) * 768 + (j0 - 1536) + tx] = f2bf(v);
  }
  __syncthreads();
  if (j0 < 1536) {
#pragma unroll
    for (int r = 0; r < 4; r++)
      Wt[(size_t)(j0 + ty + r * 8) * 768 + k0 + tx] = f2bf(tile[tx][ty + r * 8]);
  }
}

// ---------------------------------------------------------------------------
// m97-style MFMA GEMM: C[M x N] = A[M x K] * B[K x N], B given as Bt[N][K].
// All bf16 inputs. 128x128 tile, BK=32, global_load_lds width-16 staging,
// linear LDS [128][32], 2-barrier loop. 4 waves (2x2), 4x4 16x16x32 frags.
// ---------------------------------------------------------------------------
template <int OUTF32B>
__global__ __launch_bounds__(256, 3)
void k_gemm(const u16* __restrict__ A, const u16* __restrict__ Btp,
            void* __restrict__ Cp, const float* __restrict__ bias,
            int K, int lda, int ldb, int ldc,
            long bBatchStride, int rowsPerBatch) {
  __shared__ u16 As[128 * 32];
  __shared__ u16 Bs[128 * 32];
  const int tid = threadIdx.x;
  const int lane = tid & 63;
  const int wid = tid >> 6;
  const int wr = wid >> 1, wc = wid & 1;
  const int fm = lane & 15, kg = lane >> 4;
  const int m0 = blockIdx.y * 128;
  const int n0 = blockIdx.x * 128;
  const u16* Bt = Btp + (bBatchStride ? (long)(m0 / rowsPerBatch) * bBatchStride : 0);

  // staging: wave w covers rows [w*32, w*32+32) of both tiles; lane -> 16B
  const int lr = lane >> 2;          // row within 16-row chunk
  const int lc = (lane & 3) * 8;     // col element (0,8,16,24)
  const u16* gA0 = A + (size_t)(m0 + wid * 32 + lr) * lda + lc;
  const u16* gA1 = gA0 + (size_t)16 * lda;
  const u16* gB0 = Bt + (size_t)(n0 + wid * 32 + lr) * ldb + lc;
  const u16* gB1 = gB0 + (size_t)16 * ldb;
  u16* lA0 = As + wid * 1024;
  u16* lA1 = lA0 + 512;
  u16* lB0 = Bs + wid * 1024;
  u16* lB1 = lB0 + 512;

  f32x4 acc[4][4] = {};
  for (int k0 = 0; k0 < K; k0 += 32) {
    __syncthreads();                 // all waves done reading previous tile
    gll16(gA0, lA0);
    gll16(gA1, lA1);
    gll16(gB0, lB0);
    gll16(gB1, lB1);
    gA0 += 32; gA1 += 32; gB0 += 32; gB1 += 32;
    __syncthreads();                 // vmcnt drained -> tile resident
    bf16x8 af[4], bfr[4];
#pragma unroll
    for (int i = 0; i < 4; i++)
      af[i] = *(const bf16x8*)&As[(wr * 64 + i * 16 + fm) * 32 + kg * 8];
#pragma unroll
    for (int j = 0; j < 4; j++)
      bfr[j] = *(const bf16x8*)&Bs[(wc * 64 + j * 16 + fm) * 32 + kg * 8];
#pragma unroll
    for (int i = 0; i < 4; i++)
#pragma unroll
      for (int j = 0; j < 4; j++)
        acc[i][j] = __builtin_amdgcn_mfma_f32_16x16x32_bf16(af[i], bfr[j], acc[i][j], 0, 0, 0);
  }

  if constexpr (OUTF32B) {
    float* C = (float*)Cp;
#pragma unroll
    for (int j = 0; j < 4; j++) {
      const int col = n0 + wc * 64 + j * 16 + fm;
      const float bj = bias[col];
#pragma unroll
      for (int i = 0; i < 4; i++) {
        const int r0 = m0 + wr * 64 + i * 16 + kg * 4;
#pragma unroll
        for (int r = 0; r < 4; r++)
          C[(size_t)(r0 + r) * ldc + col] = acc[i][j][r] + bj;
      }
    }
  } else {
    u16* C = (u16*)Cp;
#pragma unroll
    for (int j = 0; j < 4; j++) {
      const int col = n0 + wc * 64 + j * 16 + fm;
#pragma unroll
      for (int i = 0; i < 4; i++) {
        const int r0 = m0 + wr * 64 + i * 16 + kg * 4;
#pragma unroll
        for (int r = 0; r < 4; r++)
          C[(size_t)(r0 + r) * ldc + col] = f2bf(acc[i][j][r]);
      }
    }
  }
}

// ---------------------------------------------------------------------------
// Gram: per (b,h, split s): partial G[c,d] = sum_t Q[t][c] K[t][d] over 512 t,
// plus partial squared column norms. C1 layout: [n][1536] (Q | K).
// ---------------------------------------------------------------------------
__global__ __launch_bounds__(256)
void k_gram(const u16* __restrict__ C1, float* __restrict__ Gpart,
            float* __restrict__ NqP, float* __restrict__ NkP) {
  const int s = blockIdx.x, h = blockIdx.y, b = blockIdx.z;
  const int tid = threadIdx.x;
  __shared__ float Qs[32][96];
  __shared__ float Ks[32][96];
  const int cg = tid >> 4, dg = tid & 15;
  const int c0 = cg * 6, d0 = dg * 6;
  float accg[6][6] = {};
  float accq[6] = {}, acck[6] = {};
  const size_t qbase = ((size_t)b * 4096) * 1536 + (size_t)h * 96;
  const size_t kbase = qbase + 768;
  const int t0 = s * 512;

  for (int tile = 0; tile < 16; tile++) {
    const int ts = t0 + tile * 32;
    __syncthreads();
#pragma unroll
    for (int it = 0; it < 3; it++) {
      const int idx = tid + it * 256;  // 0..767 (32 t x 24 chunks)
      const int tt = idx / 24;
      const int cc = (idx % 24) * 4;
      const size_t roff = (size_t)(ts + tt) * 1536 + cc;
      u16x4 vq = *(const u16x4*)(C1 + qbase + roff);
      u16x4 vk = *(const u16x4*)(C1 + kbase + roff);
      f32x4 fq, fk;
#pragma unroll
      for (int e = 0; e < 4; e++) {
        fq[e] = bf2f(vq[e]);
        fk[e] = bf2f(vk[e]);
      }
      *(f32x4*)&Qs[tt][cc] = fq;
      *(f32x4*)&Ks[tt][cc] = fk;
    }
    __syncthreads();
    for (int tt = 0; tt < 32; tt++) {
      f32x2 qa = *(const f32x2*)&Qs[tt][c0];
      f32x2 qb = *(const f32x2*)&Qs[tt][c0 + 2];
      f32x2 qc = *(const f32x2*)&Qs[tt][c0 + 4];
      f32x2 ka = *(const f32x2*)&Ks[tt][d0];
      f32x2 kb = *(const f32x2*)&Ks[tt][d0 + 2];
      f32x2 kc = *(const f32x2*)&Ks[tt][d0 + 4];
      float q[6] = {qa[0], qa[1], qb[0], qb[1], qc[0], qc[1]};
      float k[6] = {ka[0], ka[1], kb[0], kb[1], kc[0], kc[1]};
#pragma unroll
      for (int i = 0; i < 6; i++)
#pragma unroll
        for (int j = 0; j < 6; j++) accg[i][j] += q[i] * k[j];
      if (dg == 0) {
#pragma unroll
        for (int i = 0; i < 6; i++) accq[i] += q[i] * q[i];
      }
      if (cg == 0) {
#pragma unroll
        for (int j = 0; j < 6; j++) acck[j] += k[j] * k[j];
      }
    }
  }
  const int blk = (b * 8 + h) * 8 + s;
  float* G = Gpart + (size_t)blk * 9216;
#pragma unroll
  for (int i = 0; i < 6; i++)
#pragma unroll
    for (int j2 = 0; j2 < 3; j2++) {
      f32x2 v;
      v[0] = accg[i][j2 * 2];
      v[1] = accg[i][j2 * 2 + 1];
      *(f32x2*)&G[(c0 + i) * 96 + d0 + j2 * 2] = v;
    }
  if (dg == 0) {
#pragma unroll
    for (int i = 0; i < 6; i++) NqP[(size_t)blk * 96 + c0 + i] = accq[i];
  }
  if (cg == 0) {
#pragma unroll
    for (int j = 0; j < 6; j++) NkP[(size_t)blk * 96 + d0 + j] = acck[j];
  }
}

// ---------------------------------------------------------------------------
// Reduce partials, normalize + temperature, softmax rows -> Aattn
// ---------------------------------------------------------------------------
__global__ __launch_bounds__(128)
void k_softmax(const float* __restrict__ Gpart, const float* __restrict__ NqP,
               const float* __restrict__ NkP, const float* __restrict__ temperature,
               float* __restrict__ Aattn) {
  const int h = blockIdx.x, b = blockIdx.y;
  const int bh = b * 8 + h;
  const int tid = threadIdx.x;
  __shared__ float Gs[9216];
  __shared__ float inq[96], ink[96];
  if (tid < 96) {
    float sq = 0.f, sk = 0.f;
    for (int s = 0; s < 8; s++) {
      sq += NqP[(size_t)(bh * 8 + s) * 96 + tid];
      sk += NkP[(size_t)(bh * 8 + s) * 96 + tid];
    }
    float nq = sqrtf(sq); if (nq < EPSN) nq = EPSN;
    float nk = sqrtf(sk); if (nk < EPSN) nk = EPSN;
    inq[tid] = 1.0f / nq;
    ink[tid] = 1.0f / nk;
  }
  for (int idx = tid; idx < 9216; idx += 128) {
    float g = 0.f;
    for (int s = 0; s < 8; s++) g += Gpart[(size_t)(bh * 8 + s) * 9216 + idx];
    Gs[idx] = g;
  }
  __syncthreads();
  const float tmp = temperature[h];
  if (tid < 96) {
    const int c = tid;
    const float qn = inq[c] * tmp;
    float sv[96];
    float m = -1e30f;
#pragma unroll
    for (int d = 0; d < 96; d++) {
      float sval = Gs[c * 96 + d] * qn * ink[d];
      sv[d] = sval;
      m = fmaxf(m, sval);
    }
    float sum = 0.f;
#pragma unroll
    for (int d = 0; d < 96; d++) {
      float e = __expf(sv[d] - m);
      sv[d] = e;
      sum += e;
    }
    const float inv = 1.0f / sum;
    float* dst = Aattn + (size_t)bh * 9216 + (size_t)c * 96;
#pragma unroll
    for (int d = 0; d < 96; d++) dst[d] = sv[d] * inv;
  }
}

// ---------------------------------------------------------------------------
// WeffT[b][j][e] = sum_c A[b,h(e),c,dc(e)] * Wproj[h*96+c][j]   (bf16 out)
// ---------------------------------------------------------------------------
__global__ __launch_bounds__(256)
void k_weff(const float* __restrict__ Aattn, const float* __restrict__ Wproj,
            u16* __restrict__ Weff) {
  const int jt = blockIdx.x, h = blockIdx.y, b = blockIdx.z;
  const int bh = b * 8 + h;
  __shared__ float As2[9216];
  const int tid = threadIdx.x;
  for (int idx = tid; idx < 9216; idx += 256)
    As2[idx] = Aattn[(size_t)bh * 9216 + idx];
  __syncthreads();
  const int jloc = tid & 127;
  const int half = tid >> 7;
  const int j = jt * 128 + jloc;
  float acc[48] = {};
  for (int c = 0; c < 96; c++) {
    const float w = Wproj[(size_t)(h * 96 + c) * 768 + j];
    const f32x4* ar = (const f32x4*)&As2[c * 96 + half * 48];
#pragma unroll
    for (int v4 = 0; v4 < 12; v4++) {
      f32x4 a = ar[v4];
      acc[v4 * 4 + 0] += w * a[0];
      acc[v4 * 4 + 1] += w * a[1];
      acc[v4 * 4 + 2] += w * a[2];
      acc[v4 * 4 + 3] += w * a[3];
    }
  }
  u16* dst = Weff + ((size_t)b * 768 + j) * 768 + h * 96 + half * 48;
#pragma unroll
  for (int v4 = 0; v4 < 12; v4++) {
    u16x4 o;
    o[0] = f2bf(acc[v4 * 4 + 0]);
    o[1] = f2bf(acc[v4 * 4 + 1]);
    o[2] = f2bf(acc[v4 * 4 + 2]);
    o[3] = f2bf(acc[v4 * 4 + 3]);
    *(u16x4*)(dst + v4 * 4) = o;
  }
}

// ---------------------------------------------------------------------------
extern "C" void kernel_launch(void* const* d_in, const int* in_sizes, int n_in,
                              void* d_out, int out_size, void* d_ws, size_t ws_size,
                              hipStream_t stream) {
  const float* x = (const float*)d_in[0];        // (8,4096,768)
  const float* Wqkv = (const float*)d_in[1];     // (768,2304)
  const float* temp = (const float*)d_in[2];     // (8,1,1)
  const float* Wproj = (const float*)d_in[3];    // (768,768)
  const float* bproj = (const float*)d_in[4];    // (768,)
  float* out = (float*)d_out;                    // (8,4096,768) f32

  char* ws = (char*)d_ws;
  u16* Xh = (u16*)ws;                            // 32768x768 bf16 = 50,331,648
  u16* C1 = (u16*)(ws + 50331648);               // 32768x1536 bf16 = 100,663,296
  u16* WeffT = (u16*)(ws + 50331648);            // alias into C1 (dead after gram)
  u16* WcompT = (u16*)(ws + 67108864);           // alias into C1 (+16 MiB)
  u16* Wt = (u16*)(ws + 150994944);              // 1536x768 bf16 = 2,359,296
  u16* Wvh = (u16*)(ws + 153354240);             // 768x768 bf16 = 1,179,648
  float* Gpart = (float*)(ws + 154533888);       // 512x9216 f32 = 18,874,368
  float* NqP = (float*)(ws + 173408256);         // 512x96 f32
  float* NkP = (float*)(ws + 173604864);         // 512x96 f32
  float* Aattn = (float*)(ws + 173801472);       // 64x9216 f32 = 2,359,296
  // total ws use: 176,160,768 B

  // 1. x -> bf16
  k_cvt<<<2048, 256, 0, stream>>>(x, Xh, 3145728);
  // 2. Wqkv -> Wt (QK cols, transposed) + Wvh (V cols, row-major)
  k_wt<<<dim3(72, 24), 256, 0, stream>>>(Wqkv, Wt, Wvh);
  // 3. C1 = Xh @ Wqkv[:, :1536]  (M=32768, N=1536, K=768)
  k_gemm<0><<<dim3(12, 256), 256, 0, stream>>>(
      Xh, Wt, (void*)C1, nullptr, 768, 768, 768, 1536, 0L, 1);
  // 4. partial Gram + norms
  k_gram<<<dim3(8, 8, 8), 256, 0, stream>>>(C1, Gpart, NqP, NkP);
  // 5. softmax -> Aattn
  k_softmax<<<dim3(8, 8), 128, 0, stream>>>(Gpart, NqP, NkP, temp, Aattn);
  // 6. WeffT = blockdiag(A)^T @ Wproj (transposed, bf16)
  k_weff<<<dim3(6, 8, 8), 256, 0, stream>>>(Aattn, Wproj, WeffT);
  // 7. WcompT[b][j][k] = sum_d WeffT[b][j][d] * Wvh[k][d]  (M=6144,N=768,K=768)
  k_gemm<0><<<dim3(6, 48), 256, 0, stream>>>(
      WeffT, Wvh, (void*)WcompT, nullptr, 768, 768, 768, 768, 0L, 1);
  // 8. out = Xh[b] @ Wcomp[b] + bproj  (M=32768, N=768, K=768, f32 out)
  k_gemm<1><<<dim3(6, 256), 256, 0, stream>>>(
      Xh, WcompT, out, bproj, 768, 768, 768, 768, 589824L, 4096);
}

// Round 3
// 307.312 us; speedup vs baseline: 1.5759x; 1.2594x over previous
//
#include <hip/hip_runtime.h>
#include <cstdint>
#include <cstddef>

typedef unsigned short u16;
typedef short bf16x8 __attribute__((ext_vector_type(8)));
typedef unsigned short u16x4 __attribute__((ext_vector_type(4)));
typedef unsigned short u16x8 __attribute__((ext_vector_type(8)));
typedef float f32x4 __attribute__((ext_vector_type(4)));

#define EPSN 1e-12f

__device__ __forceinline__ u16 f2bf(float f) {
  uint32_t u = __builtin_bit_cast(uint32_t, f);
  u += 0x7FFFu + ((u >> 16) & 1u);
  return (u16)(u >> 16);
}
__device__ __forceinline__ float bf2f(u16 h) {
  uint32_t u = ((uint32_t)h) << 16;
  return __builtin_bit_cast(float, u);
}

__device__ __forceinline__ void gll16(const u16* g, u16* l) {
  __builtin_amdgcn_global_load_lds(
      (const __attribute__((address_space(1))) void*)g,
      (__attribute__((address_space(3))) void*)l, 16, 0, 0);
}

// ---------------------------------------------------------------------------
// x f32 -> Xh bf16 (row-major [b][t][k]) + XhT bf16 (transposed [b][k][t]).
// 64x64 tiles through LDS.
// ---------------------------------------------------------------------------
__global__ __launch_bounds__(256)
void k_cvtT(const float* __restrict__ x, u16* __restrict__ Xh,
            u16* __restrict__ XhT) {
  __shared__ u16 tr[64][68];  // [k][t], pad 68 keeps u16x4 reads 8B-aligned
  const int tid = threadIdx.x;
  const int t0 = blockIdx.x * 64, k0 = blockIdx.y * 64, b = blockIdx.z;
  const size_t base = ((size_t)b * 4096 + t0) * 768 + k0;
#pragma unroll
  for (int p = 0; p < 4; p++) {
    const int r = (tid >> 4) + p * 16;
    const int c = (tid & 15) * 4;
    f32x4 v = *(const f32x4*)(x + base + (size_t)r * 768 + c);
    u16x4 o;
#pragma unroll
    for (int e = 0; e < 4; e++) o[e] = f2bf(v[e]);
    *(u16x4*)(Xh + base + (size_t)r * 768 + c) = o;
    tr[c + 0][r] = o[0];
    tr[c + 1][r] = o[1];
    tr[c + 2][r] = o[2];
    tr[c + 3][r] = o[3];
  }
  __syncthreads();
  const size_t tbase = ((size_t)b * 768 + k0) * 4096 + t0;
#pragma unroll
  for (int p = 0; p < 4; p++) {
    const int kk = (tid >> 4) + p * 16;
    const int ts = (tid & 15) * 4;
    u16x4 o;
#pragma unroll
    for (int e = 0; e < 4; e++) o[e] = tr[kk][ts + e];
    *(u16x4*)(XhT + tbase + (size_t)kk * 4096 + ts) = o;
  }
}

// ---------------------------------------------------------------------------
// Wqkv (768x2304 f32): cols [0,1536) -> Wt transposed bf16 (1536x768);
//                      cols [1536,2304) -> Wvh row-major bf16 (768x768)
// ---------------------------------------------------------------------------
__global__ __launch_bounds__(256)
void k_wt(const float* __restrict__ W, u16* __restrict__ Wt, u16* __restrict__ Wvh) {
  __shared__ float tile[32][33];
  const int j0 = blockIdx.x * 32;
  const int k0 = blockIdx.y * 32;
  const int tx = threadIdx.x & 31;
  const int ty = threadIdx.x >> 5;
#pragma unroll
  for (int r = 0; r < 4; r++) {
    float v = W[(size_t)(k0 + ty + r * 8) * 2304 + j0 + tx];
    tile[ty + r * 8][tx] = v;
    if (j0 >= 1536)
      Wvh[(size_t)(k0 + ty + r * 8) * 768 + (j0 - 1536) + tx] = f2bf(v);
  }
  __syncthreads();
  if (j0 < 1536) {
#pragma unroll
    for (int r = 0; r < 4; r++)
      Wt[(size_t)(j0 + ty + r * 8) * 768 + k0 + tx] = f2bf(tile[tx][ty + r * 8]);
  }
}

// ---------------------------------------------------------------------------
// m97-style MFMA GEMM with XOR-swizzled LDS (2-way banks): C = A * Bt^T.
// 128x128 tile, BK=32, gll16 staging, z-batched: b = z/zK, s = z%zK (K-split).
// OUTF32B: f32 out + bias, else bf16 out.
// ---------------------------------------------------------------------------
template <int OUTF32B>
__global__ __launch_bounds__(256, 3)
void k_gemm(const u16* __restrict__ A, const u16* __restrict__ Btp,
            void* __restrict__ Cp, const float* __restrict__ bias,
            int K, int lda, int ldb, int ldc,
            long aZ, long bZ, long cZ, int zK, long kss) {
  __shared__ u16 As[128 * 32];
  __shared__ u16 Bs[128 * 32];
  const int tid = threadIdx.x;
  const int lane = tid & 63;
  const int wid = tid >> 6;
  const int wr = wid >> 1, wc = wid & 1;
  const int fm = lane & 15, kg = lane >> 4;
  const int m0 = blockIdx.y * 128;
  const int n0 = blockIdx.x * 128;
  const int z = blockIdx.z;
  const int bb = z / zK, ss = z % zK;
  const u16* Az = A + (long)bb * aZ + (long)ss * kss;
  const u16* Btz = Btp + (long)bb * bZ + (long)ss * kss;

  // staging: lane -> dest (row, block lane&3); source block XOR-swizzled so
  // that LDS(row, kb) holds global(row, kb ^ ((row>>1)&3))
  const int lr = lane >> 2;
  const int gk = (lane & 3) ^ ((lane >> 3) & 3);
  const u16* gA0 = Az + (size_t)(m0 + wid * 32 + lr) * lda + gk * 8;
  const u16* gA1 = gA0 + (size_t)16 * lda;
  const u16* gB0 = Btz + (size_t)(n0 + wid * 32 + lr) * ldb + gk * 8;
  const u16* gB1 = gB0 + (size_t)16 * ldb;
  u16* lA0 = As + wid * 1024;
  u16* lA1 = lA0 + 512;
  u16* lB0 = Bs + wid * 1024;
  u16* lB1 = lB0 + 512;
  const int kq = (kg ^ ((fm >> 1) & 3)) * 8;  // swizzled read block

  f32x4 acc[4][4] = {};
  for (int k0 = 0; k0 < K; k0 += 32) {
    __syncthreads();
    gll16(gA0, lA0);
    gll16(gA1, lA1);
    gll16(gB0, lB0);
    gll16(gB1, lB1);
    gA0 += 32; gA1 += 32; gB0 += 32; gB1 += 32;
    __syncthreads();
    bf16x8 af[4], bfr[4];
#pragma unroll
    for (int i = 0; i < 4; i++)
      af[i] = *(const bf16x8*)&As[(wr * 64 + i * 16 + fm) * 32 + kq];
#pragma unroll
    for (int j = 0; j < 4; j++)
      bfr[j] = *(const bf16x8*)&Bs[(wc * 64 + j * 16 + fm) * 32 + kq];
#pragma unroll
    for (int i = 0; i < 4; i++)
#pragma unroll
      for (int j = 0; j < 4; j++)
        acc[i][j] = __builtin_amdgcn_mfma_f32_16x16x32_bf16(af[i], bfr[j], acc[i][j], 0, 0, 0);
  }

  if constexpr (OUTF32B) {
    float* C = (float*)Cp + (long)z * cZ;
#pragma unroll
    for (int j = 0; j < 4; j++) {
      const int col = n0 + wc * 64 + j * 16 + fm;
      const float bj = bias[col];
#pragma unroll
      for (int i = 0; i < 4; i++) {
        const int r0 = m0 + wr * 64 + i * 16 + kg * 4;
#pragma unroll
        for (int r = 0; r < 4; r++)
          C[(size_t)(r0 + r) * ldc + col] = acc[i][j][r] + bj;
      }
    }
  } else {
    u16* C = (u16*)Cp + (long)z * cZ;
#pragma unroll
    for (int j = 0; j < 4; j++) {
      const int col = n0 + wc * 64 + j * 16 + fm;
#pragma unroll
      for (int i = 0; i < 4; i++) {
        const int r0 = m0 + wr * 64 + i * 16 + kg * 4;
#pragma unroll
        for (int r = 0; r < 4; r++)
          C[(size_t)(r0 + r) * ldc + col] = f2bf(acc[i][j][r]);
      }
    }
  }
}

// ---------------------------------------------------------------------------
// Reduce 4 bf16 K-split partials of XtX -> bf16
// ---------------------------------------------------------------------------
__global__ __launch_bounds__(256)
void k_red(const u16* __restrict__ P, u16* __restrict__ O) {
  const int b = blockIdx.y;
  const size_t r = ((size_t)blockIdx.x * 256 + threadIdx.x) * 8;
  const u16* p = P + (size_t)b * 4 * 589824 + r;
  u16x8 v0 = *(const u16x8*)(p);
  u16x8 v1 = *(const u16x8*)(p + 589824);
  u16x8 v2 = *(const u16x8*)(p + 2 * 589824);
  u16x8 v3 = *(const u16x8*)(p + 3 * 589824);
  u16x8 o;
#pragma unroll
  for (int e = 0; e < 8; e++)
    o[e] = f2bf(bf2f(v0[e]) + bf2f(v1[e]) + bf2f(v2[e]) + bf2f(v3[e]));
  *(u16x8*)(O + (size_t)b * 589824 + r) = o;
}

// ---------------------------------------------------------------------------
// Per (b,h): G = T1 * WkT^T (96x96, K=768 MFMA), nq[c]=dot(T1[c],WqT[c]),
// nk[d]=dot(T2[d],WkT[d]); then softmax rows -> Aattn.
// T layout: [b][1536][768] bf16 (rows h*96+c = T1, rows 768+h*96+d = T2).
// ---------------------------------------------------------------------------
__global__ __launch_bounds__(256)
void k_score(const u16* __restrict__ Tm, const u16* __restrict__ Wt,
             const float* __restrict__ temperature, float* __restrict__ Aattn) {
  const int h = blockIdx.x, b = blockIdx.y;
  const int bh = b * 8 + h;
  __shared__ u16 As[96 * 32];    // T1 rows (swizzled)
  __shared__ u16 Bs[96 * 32];    // WkT rows (swizzled)
  __shared__ u16 Dt2[96 * 32];   // T2 rows (linear)
  __shared__ u16 Dwq[96 * 32];   // WqT rows (linear)
  __shared__ float Gs[96 * 96];
  __shared__ float nqs[96], nks[96], invk[96];

  const int tid = threadIdx.x;
  const int lane = tid & 63;
  const int wid = tid >> 6;
  const int wr = wid >> 1, wc = wid & 1;
  const int fm = lane & 15, kg = lane >> 4;
  const int lr = lane >> 2;
  const int gkS = (lane & 3) ^ ((lane >> 3) & 3);  // swizzled source block
  const int gkL = (lane & 3);                      // linear source block
  const int kq = (kg ^ ((fm >> 1) & 3)) * 8;

  const u16* baseT1 = Tm + (size_t)b * 1179648 + (size_t)(h * 96) * 768;
  const u16* baseT2 = baseT1 + (size_t)768 * 768;
  const u16* baseWq = Wt + (size_t)(h * 96) * 768;
  const u16* baseWk = baseWq + (size_t)768 * 768;

  const u16* gsrc;
  u16* ldst;
  int gblk = gkS;
  if (wid == 0) { gsrc = baseT1; ldst = As; }
  else if (wid == 1) { gsrc = baseWk; ldst = Bs; }
  else if (wid == 2) { gsrc = baseT2; ldst = Dt2; gblk = gkL; }
  else { gsrc = baseWq; ldst = Dwq; gblk = gkL; }

  f32x4 acc[3][3] = {};
  float nqa = 0.f, nka = 0.f;
  const int sw1 = (tid < 96) ? ((tid >> 1) & 3) : 0;
  const int sw2 = (tid >= 128 && tid < 224) ? (((tid - 128) >> 1) & 3) : 0;

  for (int k0 = 0; k0 < 768; k0 += 32) {
    __syncthreads();
#pragma unroll
    for (int c = 0; c < 6; c++) {
      gll16(gsrc + (size_t)(c * 16 + lr) * 768 + k0 + gblk * 8,
            ldst + c * 512);
    }
    __syncthreads();
    bf16x8 af[3], bfr[3];
#pragma unroll
    for (int i = 0; i < 3; i++)
      af[i] = *(const bf16x8*)&As[(wr * 48 + i * 16 + fm) * 32 + kq];
#pragma unroll
    for (int j = 0; j < 3; j++)
      bfr[j] = *(const bf16x8*)&Bs[(wc * 48 + j * 16 + fm) * 32 + kq];
#pragma unroll
    for (int i = 0; i < 3; i++)
#pragma unroll
      for (int j = 0; j < 3; j++)
        acc[i][j] = __builtin_amdgcn_mfma_f32_16x16x32_bf16(af[i], bfr[j], acc[i][j], 0, 0, 0);
    // norm dots
    if (tid < 96) {
#pragma unroll
      for (int g = 0; g < 4; g++) {
        u16x8 a = *(const u16x8*)&As[tid * 32 + (g ^ sw1) * 8];
        u16x8 w = *(const u16x8*)&Dwq[tid * 32 + g * 8];
#pragma unroll
        for (int e = 0; e < 8; e++) nqa += bf2f(a[e]) * bf2f(w[e]);
      }
    } else if (tid >= 128 && tid < 224) {
      const int d = tid - 128;
#pragma unroll
      for (int g = 0; g < 4; g++) {
        u16x8 a = *(const u16x8*)&Bs[d * 32 + (g ^ sw2) * 8];
        u16x8 w = *(const u16x8*)&Dt2[d * 32 + g * 8];
#pragma unroll
        for (int e = 0; e < 8; e++) nka += bf2f(a[e]) * bf2f(w[e]);
      }
    }
  }

  if (tid < 96) nqs[tid] = nqa;
  if (tid >= 128 && tid < 224) nks[tid - 128] = nka;
#pragma unroll
  for (int i = 0; i < 3; i++)
#pragma unroll
    for (int j = 0; j < 3; j++)
#pragma unroll
      for (int r = 0; r < 4; r++)
        Gs[(wr * 48 + i * 16 + kg * 4 + r) * 96 + wc * 48 + j * 16 + fm] = acc[i][j][r];
  __syncthreads();
  if (tid < 96) invk[tid] = 1.0f / fmaxf(sqrtf(nks[tid]), EPSN);
  __syncthreads();
  if (tid < 96) {
    const int c = tid;
    const float iq = temperature[h] / fmaxf(sqrtf(nqs[c]), EPSN);
    float sv[96];
    float m = -1e30f;
#pragma unroll
    for (int d = 0; d < 96; d++) {
      float s = Gs[c * 96 + d] * iq * invk[d];
      sv[d] = s;
      m = fmaxf(m, s);
    }
    float sum = 0.f;
#pragma unroll
    for (int d = 0; d < 96; d++) {
      float e = __expf(sv[d] - m);
      sv[d] = e;
      sum += e;
    }
    const float inv = 1.0f / sum;
    float* dst = Aattn + (size_t)bh * 9216 + (size_t)c * 96;
#pragma unroll
    for (int d = 0; d < 96; d++) dst[d] = sv[d] * inv;
  }
}

// ---------------------------------------------------------------------------
// WeffT[b][j][e] = sum_c A[b,h(e),c,dc(e)] * Wproj[h*96+c][j]   (bf16 out)
// ---------------------------------------------------------------------------
__global__ __launch_bounds__(256)
void k_weff(const float* __restrict__ Aattn, const float* __restrict__ Wproj,
            u16* __restrict__ Weff) {
  const int jt = blockIdx.x, h = blockIdx.y, b = blockIdx.z;
  const int bh = b * 8 + h;
  __shared__ float As2[9216];
  const int tid = threadIdx.x;
  for (int idx = tid; idx < 9216; idx += 256)
    As2[idx] = Aattn[(size_t)bh * 9216 + idx];
  __syncthreads();
  const int jloc = tid & 127;
  const int half = tid >> 7;
  const int j = jt * 128 + jloc;
  float acc[48] = {};
  for (int c = 0; c < 96; c++) {
    const float w = Wproj[(size_t)(h * 96 + c) * 768 + j];
    const f32x4* ar = (const f32x4*)&As2[c * 96 + half * 48];
#pragma unroll
    for (int v4 = 0; v4 < 12; v4++) {
      f32x4 a = ar[v4];
      acc[v4 * 4 + 0] += w * a[0];
      acc[v4 * 4 + 1] += w * a[1];
      acc[v4 * 4 + 2] += w * a[2];
      acc[v4 * 4 + 3] += w * a[3];
    }
  }
  u16* dst = Weff + ((size_t)b * 768 + j) * 768 + h * 96 + half * 48;
#pragma unroll
  for (int v4 = 0; v4 < 12; v4++) {
    u16x4 o;
    o[0] = f2bf(acc[v4 * 4 + 0]);
    o[1] = f2bf(acc[v4 * 4 + 1]);
    o[2] = f2bf(acc[v4 * 4 + 2]);
    o[3] = f2bf(acc[v4 * 4 + 3]);
    *(u16x4*)(dst + v4 * 4) = o;
  }
}

// ---------------------------------------------------------------------------
extern "C" void kernel_launch(void* const* d_in, const int* in_sizes, int n_in,
                              void* d_out, int out_size, void* d_ws, size_t ws_size,
                              hipStream_t stream) {
  const float* x = (const float*)d_in[0];
  const float* Wqkv = (const float*)d_in[1];
  const float* temp = (const float*)d_in[2];
  const float* Wproj = (const float*)d_in[3];
  const float* bproj = (const float*)d_in[4];
  float* out = (float*)d_out;

  char* ws = (char*)d_ws;
  u16* Xh = (u16*)ws;                       // 50,331,648 B
  u16* XhT = (u16*)(ws + 50331648);         // 50,331,648 B
  u16* Wt = (u16*)(ws + 100663296);         // 2,359,296 B
  u16* Wvh = (u16*)(ws + 103022592);        // 1,179,648 B
  u16* XtXp = (u16*)(ws + 104202240);       // 32 x 589824 bf16 = 37,748,736 B
  u16* XtXbf = (u16*)(ws + 141950976);      // 8 x 589824 bf16 = 9,437,184 B
  u16* T = (u16*)(ws + 151388160);          // 8 x 1536 x 768 bf16 = 18,874,368 B
  u16* WeffT = (u16*)(ws + 151388160);      // alias: T dead after k_score
  u16* WcompT = (u16*)(ws + 160825344);     // alias into T region
  float* Aattn = (float*)(ws + 170262528);  // 64 x 9216 f32 = 2,359,296 B
  // total ws use: 172,621,824 B

  // 1. x -> Xh (row-major bf16) + XhT (transposed bf16)
  k_cvtT<<<dim3(64, 12, 8), 256, 0, stream>>>(x, Xh, XhT);
  // 2. Wqkv -> Wt (QK cols transposed) + Wvh (V cols row-major)
  k_wt<<<dim3(72, 24), 256, 0, stream>>>(Wqkv, Wt, Wvh);
  // 3. XtX partials: per (b, s): XhT_b[:, s*1024:+1024] gram, bf16 partials
  k_gemm<0><<<dim3(6, 6, 32), 256, 0, stream>>>(
      XhT, XhT, (void*)XtXp, nullptr, 1024, 4096, 4096, 768,
      3145728L, 3145728L, 589824L, 4, 1024L);
  // 4. reduce partials -> XtXbf
  k_red<<<dim3(288, 8), 256, 0, stream>>>(XtXp, XtXbf);
  // 5. T[b] = Wt @ XtXbf_b  (M=1536, N=768, K=768; XtX symmetric -> Bt=XtX)
  k_gemm<0><<<dim3(6, 12, 8), 256, 0, stream>>>(
      Wt, XtXbf, (void*)T, nullptr, 768, 768, 768, 768,
      0L, 589824L, 1179648L, 1, 0L);
  // 6. scores + softmax -> Aattn
  k_score<<<dim3(8, 8), 256, 0, stream>>>(T, Wt, temp, Aattn);
  // 7. WeffT = blockdiag(A)^T @ Wproj (transposed, bf16)
  k_weff<<<dim3(6, 8, 8), 256, 0, stream>>>(Aattn, Wproj, WeffT);
  // 8. WcompT[b][j][k] = sum_e WeffT[b][j][e] * Wvh[k][e]
  k_gemm<0><<<dim3(6, 6, 8), 256, 0, stream>>>(
      WeffT, Wvh, (void*)WcompT, nullptr, 768, 768, 768, 768,
      589824L, 0L, 589824L, 1, 0L);
  // 9. out = Xh_b @ Wcomp_b + bproj  (f32 out)
  k_gemm<1><<<dim3(6, 32, 8), 256, 0, stream>>>(
      Xh, WcompT, out, bproj, 768, 768, 768, 768,
      3145728L, 589824L, 3145728L, 1, 0L);
}

// Round 4
// 304.549 us; speedup vs baseline: 1.5901x; 1.0091x over previous
//
#include <hip/hip_runtime.h>
#include <cstdint>
#include <cstddef>

typedef unsigned short u16;
typedef short bf16x8 __attribute__((ext_vector_type(8)));
typedef unsigned short u16x4 __attribute__((ext_vector_type(4)));
typedef unsigned short u16x8 __attribute__((ext_vector_type(8)));
typedef float f32x4 __attribute__((ext_vector_type(4)));

#define EPSN 1e-12f

__device__ __forceinline__ u16 f2bf(float f) {
  uint32_t u = __builtin_bit_cast(uint32_t, f);
  u += 0x7FFFu + ((u >> 16) & 1u);
  return (u16)(u >> 16);
}
__device__ __forceinline__ float bf2f(u16 h) {
  uint32_t u = ((uint32_t)h) << 16;
  return __builtin_bit_cast(float, u);
}

__device__ __forceinline__ void gll16(const u16* g, u16* l) {
  __builtin_amdgcn_global_load_lds(
      (const __attribute__((address_space(1))) void*)g,
      (__attribute__((address_space(3))) void*)l, 16, 0, 0);
}

// ---------------------------------------------------------------------------
// x f32 -> Xh bf16 (row-major [b][t][k]) + XhT bf16 (transposed [b][k][t]).
// ---------------------------------------------------------------------------
__global__ __launch_bounds__(256)
void k_cvtT(const float* __restrict__ x, u16* __restrict__ Xh,
            u16* __restrict__ XhT) {
  __shared__ u16 tr[64][68];
  const int tid = threadIdx.x;
  const int t0 = blockIdx.x * 64, k0 = blockIdx.y * 64, b = blockIdx.z;
  const size_t base = ((size_t)b * 4096 + t0) * 768 + k0;
#pragma unroll
  for (int p = 0; p < 4; p++) {
    const int r = (tid >> 4) + p * 16;
    const int c = (tid & 15) * 4;
    f32x4 v = *(const f32x4*)(x + base + (size_t)r * 768 + c);
    u16x4 o;
#pragma unroll
    for (int e = 0; e < 4; e++) o[e] = f2bf(v[e]);
    *(u16x4*)(Xh + base + (size_t)r * 768 + c) = o;
    tr[c + 0][r] = o[0];
    tr[c + 1][r] = o[1];
    tr[c + 2][r] = o[2];
    tr[c + 3][r] = o[3];
  }
  __syncthreads();
  const size_t tbase = ((size_t)b * 768 + k0) * 4096 + t0;
#pragma unroll
  for (int p = 0; p < 4; p++) {
    const int kk = (tid >> 4) + p * 16;
    const int ts = (tid & 15) * 4;
    u16x4 o;
#pragma unroll
    for (int e = 0; e < 4; e++) o[e] = tr[kk][ts + e];
    *(u16x4*)(XhT + tbase + (size_t)kk * 4096 + ts) = o;
  }
}

// ---------------------------------------------------------------------------
// Wqkv: cols [0,1536) -> Wt transposed bf16; cols [1536,2304) -> Wvh row-major
// ---------------------------------------------------------------------------
__global__ __launch_bounds__(256)
void k_wt(const float* __restrict__ W, u16* __restrict__ Wt, u16* __restrict__ Wvh) {
  __shared__ float tile[32][33];
  const int j0 = blockIdx.x * 32;
  const int k0 = blockIdx.y * 32;
  const int tx = threadIdx.x & 31;
  const int ty = threadIdx.x >> 5;
#pragma unroll
  for (int r = 0; r < 4; r++) {
    float v = W[(size_t)(k0 + ty + r * 8) * 2304 + j0 + tx];
    tile[ty + r * 8][tx] = v;
    if (j0 >= 1536)
      Wvh[(size_t)(k0 + ty + r * 8) * 768 + (j0 - 1536) + tx] = f2bf(v);
  }
  __syncthreads();
  if (j0 < 1536) {
#pragma unroll
    for (int r = 0; r < 4; r++)
      Wt[(size_t)(j0 + ty + r * 8) * 768 + k0 + tx] = f2bf(tile[tx][ty + r * 8]);
  }
}

// ---------------------------------------------------------------------------
// m97-style MFMA GEMM, XOR-swizzled LDS, XCD-chunked block swizzle (m204).
// TRI=1: A==B Gram, blockIdx.x in [0,21) = upper-triangle 128-tile pair;
//        C written as compact [tile][128][128] bf16.
// ---------------------------------------------------------------------------
template <int OUTF32B, int TRI>
__global__ __launch_bounds__(256, 3)
void k_gemm(const u16* __restrict__ A, const u16* __restrict__ Btp,
            void* __restrict__ Cp, const float* __restrict__ bias,
            int K, int lda, int ldb, int ldc,
            long aZ, long bZ, long cZ, int zK, long kss) {
  // --- bijective XCD-chunked swizzle of the flat block index ---
  const int gx = gridDim.x, gy = gridDim.y;
  int f = blockIdx.x + gx * (blockIdx.y + gy * blockIdx.z);
  const int total = gx * gy * gridDim.z;
  const int q = total >> 3, rr = total & 7;
  const int xcd = f & 7, kk0 = f >> 3;
  f = (xcd < rr ? xcd * (q + 1) : rr * (q + 1) + (xcd - rr) * q) + kk0;
  const int bx = f % gx;
  const int tmp = f / gx;
  const int by = tmp % gy;
  const int bz = tmp / gy;

  int m0, n0;
  if constexpr (TRI) {
    const int ty = (bx >= 20) ? 5 : (bx >= 18) ? 4 : (bx >= 15) ? 3
                 : (bx >= 11) ? 2 : (bx >= 6) ? 1 : 0;
    const int txi = ty + (bx - (ty * 6 - (ty * (ty - 1)) / 2));
    m0 = ty * 128;
    n0 = txi * 128;
  } else {
    m0 = by * 128;
    n0 = bx * 128;
  }
  const int z = bz;
  const int bb = z / zK, ss = z % zK;
  const u16* Az = A + (long)bb * aZ + (long)ss * kss;
  const u16* Btz = Btp + (long)bb * bZ + (long)ss * kss;

  __shared__ u16 As[128 * 32];
  __shared__ u16 Bs[128 * 32];
  const int tid = threadIdx.x;
  const int lane = tid & 63;
  const int wid = tid >> 6;
  const int wr = wid >> 1, wc = wid & 1;
  const int fm = lane & 15, kg = lane >> 4;

  const int lr = lane >> 2;
  const int gk = (lane & 3) ^ ((lane >> 3) & 3);
  const u16* gA0 = Az + (size_t)(m0 + wid * 32 + lr) * lda + gk * 8;
  const u16* gA1 = gA0 + (size_t)16 * lda;
  const u16* gB0 = Btz + (size_t)(n0 + wid * 32 + lr) * ldb + gk * 8;
  const u16* gB1 = gB0 + (size_t)16 * ldb;
  u16* lA0 = As + wid * 1024;
  u16* lA1 = lA0 + 512;
  u16* lB0 = Bs + wid * 1024;
  u16* lB1 = lB0 + 512;
  const int kq = (kg ^ ((fm >> 1) & 3)) * 8;

  f32x4 acc[4][4] = {};
  for (int k0 = 0; k0 < K; k0 += 32) {
    __syncthreads();
    gll16(gA0, lA0);
    gll16(gA1, lA1);
    gll16(gB0, lB0);
    gll16(gB1, lB1);
    gA0 += 32; gA1 += 32; gB0 += 32; gB1 += 32;
    __syncthreads();
    bf16x8 af[4], bfr[4];
#pragma unroll
    for (int i = 0; i < 4; i++)
      af[i] = *(const bf16x8*)&As[(wr * 64 + i * 16 + fm) * 32 + kq];
#pragma unroll
    for (int j = 0; j < 4; j++)
      bfr[j] = *(const bf16x8*)&Bs[(wc * 64 + j * 16 + fm) * 32 + kq];
#pragma unroll
    for (int i = 0; i < 4; i++)
#pragma unroll
      for (int j = 0; j < 4; j++)
        acc[i][j] = __builtin_amdgcn_mfma_f32_16x16x32_bf16(af[i], bfr[j], acc[i][j], 0, 0, 0);
  }

  if constexpr (OUTF32B) {
    float* C = (float*)Cp + (long)z * cZ;
#pragma unroll
    for (int j = 0; j < 4; j++) {
      const int col = n0 + wc * 64 + j * 16 + fm;
      const float bj = bias[col];
#pragma unroll
      for (int i = 0; i < 4; i++) {
        const int r0 = m0 + wr * 64 + i * 16 + kg * 4;
#pragma unroll
        for (int r = 0; r < 4; r++)
          C[(size_t)(r0 + r) * ldc + col] = acc[i][j][r] + bj;
      }
    }
  } else {
    const int rb = TRI ? 0 : m0;
    const int cb = TRI ? 0 : n0;
    const int ld = TRI ? 128 : ldc;
    u16* C = (u16*)Cp + (long)z * cZ + (TRI ? (long)bx * 16384 : 0L);
#pragma unroll
    for (int j = 0; j < 4; j++) {
      const int col = cb + wc * 64 + j * 16 + fm;
#pragma unroll
      for (int i = 0; i < 4; i++) {
        const int r0 = rb + wr * 64 + i * 16 + kg * 4;
#pragma unroll
        for (int r = 0; r < 4; r++)
          C[(size_t)(r0 + r) * ld + col] = f2bf(acc[i][j][r]);
      }
    }
  }
}

// ---------------------------------------------------------------------------
// Reduce 4 K-split triangle partials -> full square XtXbf (bf16), mirroring
// lower-triangle output tiles via LDS transpose.
// grid (36, 8): blockIdx.x = ti*6+tj output 128x128 tile.
// ---------------------------------------------------------------------------
__global__ __launch_bounds__(256)
void k_red(const u16* __restrict__ P, u16* __restrict__ O) {
  const int b = blockIdx.y;
  const int ti = blockIdx.x / 6, tj = blockIdx.x % 6;
  const bool mirror = ti > tj;
  const int a = mirror ? tj : ti;
  const int c2 = mirror ? ti : tj;
  const int src = a * 6 - (a * (a - 1)) / 2 + (c2 - a);
  __shared__ u16 lt[128 * 128];
  const int tid = threadIdx.x;
  const int r = tid >> 1;
  const int ch = (tid & 1) * 64;
  float acc[64] = {};
  for (int s = 0; s < 4; s++) {
    const u16* p = P + ((size_t)(b * 4 + s) * 344064 + (size_t)src * 16384);
    __syncthreads();
#pragma unroll
    for (int it = 0; it < 8; it++) {
      const int idx = (tid + it * 256) * 8;
      *(u16x8*)&lt[idx] = *(const u16x8*)(p + idx);
    }
    __syncthreads();
    if (!mirror) {
#pragma unroll
      for (int e = 0; e < 64; e++) acc[e] += bf2f(lt[r * 128 + ch + e]);
    } else {
#pragma unroll
      for (int e = 0; e < 64; e++) acc[e] += bf2f(lt[(ch + e) * 128 + r]);
    }
  }
  u16* o = O + (size_t)b * 589824 + (size_t)(ti * 128 + r) * 768 + tj * 128 + ch;
#pragma unroll
  for (int v8 = 0; v8 < 8; v8++) {
    u16x8 w;
#pragma unroll
    for (int e = 0; e < 8; e++) w[e] = f2bf(acc[v8 * 8 + e]);
    *(u16x8*)(o + v8 * 8) = w;
  }
}

// ---------------------------------------------------------------------------
// Per (b,h): G = T1 * WkT^T, norms as dots, softmax -> Aattn
// ---------------------------------------------------------------------------
__global__ __launch_bounds__(256)
void k_score(const u16* __restrict__ Tm, const u16* __restrict__ Wt,
             const float* __restrict__ temperature, float* __restrict__ Aattn) {
  const int h = blockIdx.x, b = blockIdx.y;
  const int bh = b * 8 + h;
  __shared__ u16 As[96 * 32];
  __shared__ u16 Bs[96 * 32];
  __shared__ u16 Dt2[96 * 32];
  __shared__ u16 Dwq[96 * 32];
  __shared__ float Gs[96 * 96];
  __shared__ float nqs[96], nks[96], invk[96];

  const int tid = threadIdx.x;
  const int lane = tid & 63;
  const int wid = tid >> 6;
  const int wr = wid >> 1, wc = wid & 1;
  const int fm = lane & 15, kg = lane >> 4;
  const int lr = lane >> 2;
  const int gkS = (lane & 3) ^ ((lane >> 3) & 3);
  const int gkL = (lane & 3);
  const int kq = (kg ^ ((fm >> 1) & 3)) * 8;

  const u16* baseT1 = Tm + (size_t)b * 1179648 + (size_t)(h * 96) * 768;
  const u16* baseT2 = baseT1 + (size_t)768 * 768;
  const u16* baseWq = Wt + (size_t)(h * 96) * 768;
  const u16* baseWk = baseWq + (size_t)768 * 768;

  const u16* gsrc;
  u16* ldst;
  int gblk = gkS;
  if (wid == 0) { gsrc = baseT1; ldst = As; }
  else if (wid == 1) { gsrc = baseWk; ldst = Bs; }
  else if (wid == 2) { gsrc = baseT2; ldst = Dt2; gblk = gkL; }
  else { gsrc = baseWq; ldst = Dwq; gblk = gkL; }

  f32x4 acc[3][3] = {};
  float nqa = 0.f, nka = 0.f;
  const int sw1 = (tid < 96) ? ((tid >> 1) & 3) : 0;
  const int sw2 = (tid >= 128 && tid < 224) ? (((tid - 128) >> 1) & 3) : 0;

  for (int k0 = 0; k0 < 768; k0 += 32) {
    __syncthreads();
#pragma unroll
    for (int c = 0; c < 6; c++) {
      gll16(gsrc + (size_t)(c * 16 + lr) * 768 + k0 + gblk * 8,
            ldst + c * 512);
    }
    __syncthreads();
    bf16x8 af[3], bfr[3];
#pragma unroll
    for (int i = 0; i < 3; i++)
      af[i] = *(const bf16x8*)&As[(wr * 48 + i * 16 + fm) * 32 + kq];
#pragma unroll
    for (int j = 0; j < 3; j++)
      bfr[j] = *(const bf16x8*)&Bs[(wc * 48 + j * 16 + fm) * 32 + kq];
#pragma unroll
    for (int i = 0; i < 3; i++)
#pragma unroll
      for (int j = 0; j < 3; j++)
        acc[i][j] = __builtin_amdgcn_mfma_f32_16x16x32_bf16(af[i], bfr[j], acc[i][j], 0, 0, 0);
    if (tid < 96) {
#pragma unroll
      for (int g = 0; g < 4; g++) {
        u16x8 av = *(const u16x8*)&As[tid * 32 + (g ^ sw1) * 8];
        u16x8 w = *(const u16x8*)&Dwq[tid * 32 + g * 8];
#pragma unroll
        for (int e = 0; e < 8; e++) nqa += bf2f(av[e]) * bf2f(w[e]);
      }
    } else if (tid >= 128 && tid < 224) {
      const int d = tid - 128;
#pragma unroll
      for (int g = 0; g < 4; g++) {
        u16x8 av = *(const u16x8*)&Bs[d * 32 + (g ^ sw2) * 8];
        u16x8 w = *(const u16x8*)&Dt2[d * 32 + g * 8];
#pragma unroll
        for (int e = 0; e < 8; e++) nka += bf2f(av[e]) * bf2f(w[e]);
      }
    }
  }

  if (tid < 96) nqs[tid] = nqa;
  if (tid >= 128 && tid < 224) nks[tid - 128] = nka;
#pragma unroll
  for (int i = 0; i < 3; i++)
#pragma unroll
    for (int j = 0; j < 3; j++)
#pragma unroll
      for (int r = 0; r < 4; r++)
        Gs[(wr * 48 + i * 16 + kg * 4 + r) * 96 + wc * 48 + j * 16 + fm] = acc[i][j][r];
  __syncthreads();
  if (tid < 96) invk[tid] = 1.0f / fmaxf(sqrtf(nks[tid]), EPSN);
  __syncthreads();
  if (tid < 96) {
    const int c = tid;
    const float iq = temperature[h] / fmaxf(sqrtf(nqs[c]), EPSN);
    float sv[96];
    float m = -1e30f;
#pragma unroll
    for (int d = 0; d < 96; d++) {
      float s = Gs[c * 96 + d] * iq * invk[d];
      sv[d] = s;
      m = fmaxf(m, s);
    }
    float sum = 0.f;
#pragma unroll
    for (int d = 0; d < 96; d++) {
      float e = __expf(sv[d] - m);
      sv[d] = e;
      sum += e;
    }
    const float inv = 1.0f / sum;
    float* dst = Aattn + (size_t)bh * 9216 + (size_t)c * 96;
#pragma unroll
    for (int d = 0; d < 96; d++) dst[d] = sv[d] * inv;
  }
}

// ---------------------------------------------------------------------------
// WeffT[b][j][e] = sum_c A[b,h(e),c,dc(e)] * Wproj[h*96+c][j]   (bf16 out)
// ---------------------------------------------------------------------------
__global__ __launch_bounds__(256)
void k_weff(const float* __restrict__ Aattn, const float* __restrict__ Wproj,
            u16* __restrict__ Weff) {
  const int jt = blockIdx.x, h = blockIdx.y, b = blockIdx.z;
  const int bh = b * 8 + h;
  __shared__ float As2[9216];
  const int tid = threadIdx.x;
  for (int idx = tid; idx < 9216; idx += 256)
    As2[idx] = Aattn[(size_t)bh * 9216 + idx];
  __syncthreads();
  const int jloc = tid & 127;
  const int half = tid >> 7;
  const int j = jt * 128 + jloc;
  float acc[48] = {};
  for (int c = 0; c < 96; c++) {
    const float w = Wproj[(size_t)(h * 96 + c) * 768 + j];
    const f32x4* ar = (const f32x4*)&As2[c * 96 + half * 48];
#pragma unroll
    for (int v4 = 0; v4 < 12; v4++) {
      f32x4 av = ar[v4];
      acc[v4 * 4 + 0] += w * av[0];
      acc[v4 * 4 + 1] += w * av[1];
      acc[v4 * 4 + 2] += w * av[2];
      acc[v4 * 4 + 3] += w * av[3];
    }
  }
  u16* dst = Weff + ((size_t)b * 768 + j) * 768 + h * 96 + half * 48;
#pragma unroll
  for (int v4 = 0; v4 < 12; v4++) {
    u16x4 o;
    o[0] = f2bf(acc[v4 * 4 + 0]);
    o[1] = f2bf(acc[v4 * 4 + 1]);
    o[2] = f2bf(acc[v4 * 4 + 2]);
    o[3] = f2bf(acc[v4 * 4 + 3]);
    *(u16x4*)(dst + v4 * 4) = o;
  }
}

// ---------------------------------------------------------------------------
extern "C" void kernel_launch(void* const* d_in, const int* in_sizes, int n_in,
                              void* d_out, int out_size, void* d_ws, size_t ws_size,
                              hipStream_t stream) {
  const float* x = (const float*)d_in[0];
  const float* Wqkv = (const float*)d_in[1];
  const float* temp = (const float*)d_in[2];
  const float* Wproj = (const float*)d_in[3];
  const float* bproj = (const float*)d_in[4];
  float* out = (float*)d_out;

  char* ws = (char*)d_ws;
  u16* Xh = (u16*)ws;                       // 50,331,648 B
  u16* XhT = (u16*)(ws + 50331648);         // 50,331,648 B
  u16* Wt = (u16*)(ws + 100663296);         // 2,359,296 B
  u16* Wvh = (u16*)(ws + 103022592);        // 1,179,648 B
  u16* XtXp = (u16*)(ws + 104202240);       // 32 z x 21 tiles x 16384 bf16 = 22,020,096 B
  u16* XtXbf = (u16*)(ws + 141950976);      // 8 x 589824 bf16 = 9,437,184 B
  u16* T = (u16*)(ws + 151388160);          // 8 x 1536 x 768 bf16 = 18,874,368 B
  u16* WeffT = (u16*)(ws + 151388160);      // alias: T dead after k_score
  u16* WcompT = (u16*)(ws + 160825344);
  float* Aattn = (float*)(ws + 170262528);  // 64 x 9216 f32
  // total ws use: 172,621,824 B

  // 1. x -> Xh + XhT
  k_cvtT<<<dim3(64, 12, 8), 256, 0, stream>>>(x, Xh, XhT);
  // 2. Wqkv -> Wt + Wvh
  k_wt<<<dim3(72, 24), 256, 0, stream>>>(Wqkv, Wt, Wvh);
  // 3. XtX triangle partials: per (b,s), 21 tile-pairs
  k_gemm<0, 1><<<dim3(21, 1, 32), 256, 0, stream>>>(
      XhT, XhT, (void*)XtXp, nullptr, 1024, 4096, 4096, 0,
      3145728L, 3145728L, 344064L, 4, 1024L);
  // 4. reduce + mirror -> XtXbf (full square)
  k_red<<<dim3(36, 8), 256, 0, stream>>>(XtXp, XtXbf);
  // 5. T[b] = Wt @ XtXbf_b (symmetric -> Bt=XtX)
  k_gemm<0, 0><<<dim3(6, 12, 8), 256, 0, stream>>>(
      Wt, XtXbf, (void*)T, nullptr, 768, 768, 768, 768,
      0L, 589824L, 1179648L, 1, 0L);
  // 6. scores + softmax -> Aattn
  k_score<<<dim3(8, 8), 256, 0, stream>>>(T, Wt, temp, Aattn);
  // 7. WeffT = blockdiag(A)^T @ Wproj
  k_weff<<<dim3(6, 8, 8), 256, 0, stream>>>(Aattn, Wproj, WeffT);
  // 8. WcompT[b][j][k] = sum_e WeffT[b][j][e] * Wvh[k][e]
  k_gemm<0, 0><<<dim3(6, 6, 8), 256, 0, stream>>>(
      WeffT, Wvh, (void*)WcompT, nullptr, 768, 768, 768, 768,
      589824L, 0L, 589824L, 1, 0L);
  // 9. out = Xh_b @ Wcomp_b + bproj (f32 out)
  k_gemm<1, 0><<<dim3(6, 32, 8), 256, 0, stream>>>(
      Xh, WcompT, out, bproj, 768, 768, 768, 768,
      3145728L, 589824L, 3145728L, 1, 0L);
}

// Round 5
// 297.249 us; speedup vs baseline: 1.6292x; 1.0246x over previous
//
#include <hip/hip_runtime.h>
#include <cstdint>
#include <cstddef>

typedef unsigned short u16;
typedef short bf16x8 __attribute__((ext_vector_type(8)));
typedef unsigned short u16x4 __attribute__((ext_vector_type(4)));
typedef unsigned short u16x8 __attribute__((ext_vector_type(8)));
typedef float f32x4 __attribute__((ext_vector_type(4)));

#define EPSN 1e-12f

__device__ __forceinline__ u16 f2bf(float f) {
  uint32_t u = __builtin_bit_cast(uint32_t, f);
  u += 0x7FFFu + ((u >> 16) & 1u);
  return (u16)(u >> 16);
}
__device__ __forceinline__ float bf2f(u16 h) {
  uint32_t u = ((uint32_t)h) << 16;
  return __builtin_bit_cast(float, u);
}

__device__ __forceinline__ void gll16(const u16* g, u16* l) {
  __builtin_amdgcn_global_load_lds(
      (const __attribute__((address_space(1))) void*)g,
      (__attribute__((address_space(3))) void*)l, 16, 0, 0);
}

// ---------------------------------------------------------------------------
// x f32 -> Xh bf16 (row-major [b][t][k]) + XhT bf16 (transposed [b][k][t]).
// ---------------------------------------------------------------------------
__global__ __launch_bounds__(256)
void k_cvtT(const float* __restrict__ x, u16* __restrict__ Xh,
            u16* __restrict__ XhT) {
  __shared__ u16 tr[64][68];
  const int tid = threadIdx.x;
  const int t0 = blockIdx.x * 64, k0 = blockIdx.y * 64, b = blockIdx.z;
  const size_t base = ((size_t)b * 4096 + t0) * 768 + k0;
#pragma unroll
  for (int p = 0; p < 4; p++) {
    const int r = (tid >> 4) + p * 16;
    const int c = (tid & 15) * 4;
    f32x4 v = *(const f32x4*)(x + base + (size_t)r * 768 + c);
    u16x4 o;
#pragma unroll
    for (int e = 0; e < 4; e++) o[e] = f2bf(v[e]);
    *(u16x4*)(Xh + base + (size_t)r * 768 + c) = o;
    tr[c + 0][r] = o[0];
    tr[c + 1][r] = o[1];
    tr[c + 2][r] = o[2];
    tr[c + 3][r] = o[3];
  }
  __syncthreads();
  const size_t tbase = ((size_t)b * 768 + k0) * 4096 + t0;
#pragma unroll
  for (int p = 0; p < 4; p++) {
    const int kk = (tid >> 4) + p * 16;
    const int ts = (tid & 15) * 4;
    u16x4 o;
#pragma unroll
    for (int e = 0; e < 4; e++) o[e] = tr[kk][ts + e];
    *(u16x4*)(XhT + tbase + (size_t)kk * 4096 + ts) = o;
  }
}

// ---------------------------------------------------------------------------
// Wqkv: cols [0,1536) -> Wt transposed bf16; cols [1536,2304) -> Wvh row-major
// ---------------------------------------------------------------------------
__global__ __launch_bounds__(256)
void k_wt(const float* __restrict__ W, u16* __restrict__ Wt, u16* __restrict__ Wvh) {
  __shared__ float tile[32][33];
  const int j0 = blockIdx.x * 32;
  const int k0 = blockIdx.y * 32;
  const int tx = threadIdx.x & 31;
  const int ty = threadIdx.x >> 5;
#pragma unroll
  for (int r = 0; r < 4; r++) {
    float v = W[(size_t)(k0 + ty + r * 8) * 2304 + j0 + tx];
    tile[ty + r * 8][tx] = v;
    if (j0 >= 1536)
      Wvh[(size_t)(k0 + ty + r * 8) * 768 + (j0 - 1536) + tx] = f2bf(v);
  }
  __syncthreads();
  if (j0 < 1536) {
#pragma unroll
    for (int r = 0; r < 4; r++)
      Wt[(size_t)(j0 + ty + r * 8) * 768 + k0 + tx] = f2bf(tile[tx][ty + r * 8]);
  }
}

// ---------------------------------------------------------------------------
// Pipelined MFMA GEMM: 128x128 tile, BK=32, 3-slot LDS ring, counted vmcnt
// (never 0 mid-loop), raw barriers, XOR-swizzled LDS, XCD-chunked swizzle.
// TRI=1: A==B Gram triangle (21 tile-pairs), compact C tiles.
// ---------------------------------------------------------------------------
template <int OUTF32B, int TRI>
__global__ __launch_bounds__(256, 3)
void k_gemm(const u16* __restrict__ A, const u16* __restrict__ Btp,
            void* __restrict__ Cp, const float* __restrict__ bias,
            int K, int lda, int ldb, int ldc,
            long aZ, long bZ, long cZ, int zK, long kss) {
  // --- bijective XCD-chunked swizzle of the flat block index ---
  const int gx = gridDim.x, gy = gridDim.y;
  int f = blockIdx.x + gx * (blockIdx.y + gy * blockIdx.z);
  const int total = gx * gy * gridDim.z;
  const int q = total >> 3, rr = total & 7;
  const int xcd = f & 7, kk0 = f >> 3;
  f = (xcd < rr ? xcd * (q + 1) : rr * (q + 1) + (xcd - rr) * q) + kk0;
  const int bx = f % gx;
  const int tmp = f / gx;
  const int by = tmp % gy;
  const int bz = tmp / gy;

  int m0, n0;
  if constexpr (TRI) {
    const int ty = (bx >= 20) ? 5 : (bx >= 18) ? 4 : (bx >= 15) ? 3
                 : (bx >= 11) ? 2 : (bx >= 6) ? 1 : 0;
    const int txi = ty + (bx - (ty * 6 - (ty * (ty - 1)) / 2));
    m0 = ty * 128;
    n0 = txi * 128;
  } else {
    m0 = by * 128;
    n0 = bx * 128;
  }
  const int z = bz;
  const int bb = z / zK, ss = z % zK;
  const u16* Az = A + (long)bb * aZ + (long)ss * kss;
  const u16* Btz = Btp + (long)bb * bZ + (long)ss * kss;

  __shared__ u16 As[3 * 128 * 32];
  __shared__ u16 Bs[3 * 128 * 32];
  const int tid = threadIdx.x;
  const int lane = tid & 63;
  const int wid = tid >> 6;
  const int wr = wid >> 1, wc = wid & 1;
  const int fm = lane & 15, kg = lane >> 4;

  const int lr = lane >> 2;
  const int gk = (lane & 3) ^ ((lane >> 3) & 3);
  const u16* gA = Az + (size_t)(m0 + wid * 32 + lr) * lda + gk * 8;
  const u16* gB = Btz + (size_t)(n0 + wid * 32 + lr) * ldb + gk * 8;
  const size_t a16 = (size_t)16 * lda, b16 = (size_t)16 * ldb;
  u16* lA = As + wid * 1024;
  u16* lB = Bs + wid * 1024;
  const int kq = (kg ^ ((fm >> 1) & 3)) * 8;

  auto STAGE = [&](int slot, int ko) {
    u16* la = lA + slot * 4096;
    u16* lb = lB + slot * 4096;
    gll16(gA + ko, la);
    gll16(gA + ko + a16, la + 512);
    gll16(gB + ko, lb);
    gll16(gB + ko + b16, lb + 512);
  };

  const int nt = K >> 5;   // >= 3 for all call sites
  STAGE(0, 0);
  STAGE(1, 32);
  int sC = 0, sN = 1, sS = 2;

  f32x4 acc[4][4] = {};
  for (int t = 0; t < nt; ++t) {
    if (t + 2 < nt) {
      STAGE(sS, (t + 2) * 32);
      __builtin_amdgcn_sched_barrier(0);
      asm volatile("s_waitcnt vmcnt(8)" ::: "memory");
    } else if (t + 2 == nt) {
      asm volatile("s_waitcnt vmcnt(4)" ::: "memory");
    } else {
      asm volatile("s_waitcnt vmcnt(0)" ::: "memory");
    }
    __builtin_amdgcn_sched_barrier(0);
    __builtin_amdgcn_s_barrier();          // tile t resident for all waves
    __builtin_amdgcn_sched_barrier(0);

    const u16* as_ = As + sC * 4096;
    const u16* bs_ = Bs + sC * 4096;
    bf16x8 af[4], bfr[4];
#pragma unroll
    for (int i = 0; i < 4; i++)
      af[i] = *(const bf16x8*)&as_[(wr * 64 + i * 16 + fm) * 32 + kq];
#pragma unroll
    for (int j = 0; j < 4; j++)
      bfr[j] = *(const bf16x8*)&bs_[(wc * 64 + j * 16 + fm) * 32 + kq];
    asm volatile("s_waitcnt lgkmcnt(0)" ::: "memory");
    __builtin_amdgcn_sched_barrier(0);
    __builtin_amdgcn_s_barrier();          // all reads of tile t done
    __builtin_amdgcn_sched_barrier(0);

#pragma unroll
    for (int i = 0; i < 4; i++)
#pragma unroll
      for (int j = 0; j < 4; j++)
        acc[i][j] = __builtin_amdgcn_mfma_f32_16x16x32_bf16(af[i], bfr[j], acc[i][j], 0, 0, 0);

    const int t2 = sC; sC = sN; sN = sS; sS = t2;
  }

  if constexpr (OUTF32B) {
    float* C = (float*)Cp + (long)z * cZ;
#pragma unroll
    for (int j = 0; j < 4; j++) {
      const int col = n0 + wc * 64 + j * 16 + fm;
      const float bj = bias[col];
#pragma unroll
      for (int i = 0; i < 4; i++) {
        const int r0 = m0 + wr * 64 + i * 16 + kg * 4;
#pragma unroll
        for (int r = 0; r < 4; r++)
          C[(size_t)(r0 + r) * ldc + col] = acc[i][j][r] + bj;
      }
    }
  } else {
    const int rb = TRI ? 0 : m0;
    const int cb = TRI ? 0 : n0;
    const int ld = TRI ? 128 : ldc;
    u16* C = (u16*)Cp + (long)z * cZ + (TRI ? (long)bx * 16384 : 0L);
#pragma unroll
    for (int j = 0; j < 4; j++) {
      const int col = cb + wc * 64 + j * 16 + fm;
#pragma unroll
      for (int i = 0; i < 4; i++) {
        const int r0 = rb + wr * 64 + i * 16 + kg * 4;
#pragma unroll
        for (int r = 0; r < 4; r++)
          C[(size_t)(r0 + r) * ld + col] = f2bf(acc[i][j][r]);
      }
    }
  }
}

// ---------------------------------------------------------------------------
// Reduce 4 K-split triangle partials -> full square XtXbf (bf16), mirroring
// lower-triangle output tiles via LDS transpose. grid (36, 8).
// ---------------------------------------------------------------------------
__global__ __launch_bounds__(256)
void k_red(const u16* __restrict__ P, u16* __restrict__ O) {
  const int b = blockIdx.y;
  const int ti = blockIdx.x / 6, tj = blockIdx.x % 6;
  const bool mirror = ti > tj;
  const int a = mirror ? tj : ti;
  const int c2 = mirror ? ti : tj;
  const int src = a * 6 - (a * (a - 1)) / 2 + (c2 - a);
  __shared__ u16 lt[128 * 128];
  const int tid = threadIdx.x;
  const int r = tid >> 1;
  const int ch = (tid & 1) * 64;
  float acc[64] = {};
  for (int s = 0; s < 4; s++) {
    const u16* p = P + ((size_t)(b * 4 + s) * 344064 + (size_t)src * 16384);
    __syncthreads();
#pragma unroll
    for (int it = 0; it < 8; it++) {
      const int idx = (tid + it * 256) * 8;
      *(u16x8*)&lt[idx] = *(const u16x8*)(p + idx);
    }
    __syncthreads();
    if (!mirror) {
#pragma unroll
      for (int e = 0; e < 64; e++) acc[e] += bf2f(lt[r * 128 + ch + e]);
    } else {
#pragma unroll
      for (int e = 0; e < 64; e++) acc[e] += bf2f(lt[(ch + e) * 128 + r]);
    }
  }
  u16* o = O + (size_t)b * 589824 + (size_t)(ti * 128 + r) * 768 + tj * 128 + ch;
#pragma unroll
  for (int v8 = 0; v8 < 8; v8++) {
    u16x8 w;
#pragma unroll
    for (int e = 0; e < 8; e++) w[e] = f2bf(acc[v8 * 8 + e]);
    *(u16x8*)(o + v8 * 8) = w;
  }
}

// ---------------------------------------------------------------------------
// Per (b,h): G = T1 * WkT^T, norms as dots, softmax -> Aattn
// ---------------------------------------------------------------------------
__global__ __launch_bounds__(256)
void k_score(const u16* __restrict__ Tm, const u16* __restrict__ Wt,
             const float* __restrict__ temperature, float* __restrict__ Aattn) {
  const int h = blockIdx.x, b = blockIdx.y;
  const int bh = b * 8 + h;
  __shared__ u16 As[96 * 32];
  __shared__ u16 Bs[96 * 32];
  __shared__ u16 Dt2[96 * 32];
  __shared__ u16 Dwq[96 * 32];
  __shared__ float Gs[96 * 96];
  __shared__ float nqs[96], nks[96], invk[96];

  const int tid = threadIdx.x;
  const int lane = tid & 63;
  const int wid = tid >> 6;
  const int wr = wid >> 1, wc = wid & 1;
  const int fm = lane & 15, kg = lane >> 4;
  const int lr = lane >> 2;
  const int gkS = (lane & 3) ^ ((lane >> 3) & 3);
  const int gkL = (lane & 3);
  const int kq = (kg ^ ((fm >> 1) & 3)) * 8;

  const u16* baseT1 = Tm + (size_t)b * 1179648 + (size_t)(h * 96) * 768;
  const u16* baseT2 = baseT1 + (size_t)768 * 768;
  const u16* baseWq = Wt + (size_t)(h * 96) * 768;
  const u16* baseWk = baseWq + (size_t)768 * 768;

  const u16* gsrc;
  u16* ldst;
  int gblk = gkS;
  if (wid == 0) { gsrc = baseT1; ldst = As; }
  else if (wid == 1) { gsrc = baseWk; ldst = Bs; }
  else if (wid == 2) { gsrc = baseT2; ldst = Dt2; gblk = gkL; }
  else { gsrc = baseWq; ldst = Dwq; gblk = gkL; }

  f32x4 acc[3][3] = {};
  float nqa = 0.f, nka = 0.f;
  const int sw1 = (tid < 96) ? ((tid >> 1) & 3) : 0;
  const int sw2 = (tid >= 128 && tid < 224) ? (((tid - 128) >> 1) & 3) : 0;

  for (int k0 = 0; k0 < 768; k0 += 32) {
    __syncthreads();
#pragma unroll
    for (int c = 0; c < 6; c++) {
      gll16(gsrc + (size_t)(c * 16 + lr) * 768 + k0 + gblk * 8,
            ldst + c * 512);
    }
    __syncthreads();
    bf16x8 af[3], bfr[3];
#pragma unroll
    for (int i = 0; i < 3; i++)
      af[i] = *(const bf16x8*)&As[(wr * 48 + i * 16 + fm) * 32 + kq];
#pragma unroll
    for (int j = 0; j < 3; j++)
      bfr[j] = *(const bf16x8*)&Bs[(wc * 48 + j * 16 + fm) * 32 + kq];
#pragma unroll
    for (int i = 0; i < 3; i++)
#pragma unroll
      for (int j = 0; j < 3; j++)
        acc[i][j] = __builtin_amdgcn_mfma_f32_16x16x32_bf16(af[i], bfr[j], acc[i][j], 0, 0, 0);
    if (tid < 96) {
#pragma unroll
      for (int g = 0; g < 4; g++) {
        u16x8 av = *(const u16x8*)&As[tid * 32 + (g ^ sw1) * 8];
        u16x8 w = *(const u16x8*)&Dwq[tid * 32 + g * 8];
#pragma unroll
        for (int e = 0; e < 8; e++) nqa += bf2f(av[e]) * bf2f(w[e]);
      }
    } else if (tid >= 128 && tid < 224) {
      const int d = tid - 128;
#pragma unroll
      for (int g = 0; g < 4; g++) {
        u16x8 av = *(const u16x8*)&Bs[d * 32 + (g ^ sw2) * 8];
        u16x8 w = *(const u16x8*)&Dt2[d * 32 + g * 8];
#pragma unroll
        for (int e = 0; e < 8; e++) nka += bf2f(av[e]) * bf2f(w[e]);
      }
    }
  }

  if (tid < 96) nqs[tid] = nqa;
  if (tid >= 128 && tid < 224) nks[tid - 128] = nka;
#pragma unroll
  for (int i = 0; i < 3; i++)
#pragma unroll
    for (int j = 0; j < 3; j++)
#pragma unroll
      for (int r = 0; r < 4; r++)
        Gs[(wr * 48 + i * 16 + kg * 4 + r) * 96 + wc * 48 + j * 16 + fm] = acc[i][j][r];
  __syncthreads();
  if (tid < 96) invk[tid] = 1.0f / fmaxf(sqrtf(nks[tid]), EPSN);
  __syncthreads();
  if (tid < 96) {
    const int c = tid;
    const float iq = temperature[h] / fmaxf(sqrtf(nqs[c]), EPSN);
    float sv[96];
    float m = -1e30f;
#pragma unroll
    for (int d = 0; d < 96; d++) {
      float s = Gs[c * 96 + d] * iq * invk[d];
      sv[d] = s;
      m = fmaxf(m, s);
    }
    float sum = 0.f;
#pragma unroll
    for (int d = 0; d < 96; d++) {
      float e = __expf(sv[d] - m);
      sv[d] = e;
      sum += e;
    }
    const float inv = 1.0f / sum;
    float* dst = Aattn + (size_t)bh * 9216 + (size_t)c * 96;
#pragma unroll
    for (int d = 0; d < 96; d++) dst[d] = sv[d] * inv;
  }
}

// ---------------------------------------------------------------------------
// WeffT[b][j][e] = sum_c A[b,h(e),c,dc(e)] * Wproj[h*96+c][j]   (bf16 out)
// ---------------------------------------------------------------------------
__global__ __launch_bounds__(256)
void k_weff(const float* __restrict__ Aattn, const float* __restrict__ Wproj,
            u16* __restrict__ Weff) {
  const int jt = blockIdx.x, h = blockIdx.y, b = blockIdx.z;
  const int bh = b * 8 + h;
  __shared__ float As2[9216];
  const int tid = threadIdx.x;
  for (int idx = tid; idx < 9216; idx += 256)
    As2[idx] = Aattn[(size_t)bh * 9216 + idx];
  __syncthreads();
  const int jloc = tid & 127;
  const int half = tid >> 7;
  const int j = jt * 128 + jloc;
  float acc[48] = {};
  for (int c = 0; c < 96; c++) {
    const float w = Wproj[(size_t)(h * 96 + c) * 768 + j];
    const f32x4* ar = (const f32x4*)&As2[c * 96 + half * 48];
#pragma unroll
    for (int v4 = 0; v4 < 12; v4++) {
      f32x4 av = ar[v4];
      acc[v4 * 4 + 0] += w * av[0];
      acc[v4 * 4 + 1] += w * av[1];
      acc[v4 * 4 + 2] += w * av[2];
      acc[v4 * 4 + 3] += w * av[3];
    }
  }
  u16* dst = Weff + ((size_t)b * 768 + j) * 768 + h * 96 + half * 48;
#pragma unroll
  for (int v4 = 0; v4 < 12; v4++) {
    u16x4 o;
    o[0] = f2bf(acc[v4 * 4 + 0]);
    o[1] = f2bf(acc[v4 * 4 + 1]);
    o[2] = f2bf(acc[v4 * 4 + 2]);
    o[3] = f2bf(acc[v4 * 4 + 3]);
    *(u16x4*)(dst + v4 * 4) = o;
  }
}

// ---------------------------------------------------------------------------
extern "C" void kernel_launch(void* const* d_in, const int* in_sizes, int n_in,
                              void* d_out, int out_size, void* d_ws, size_t ws_size,
                              hipStream_t stream) {
  const float* x = (const float*)d_in[0];
  const float* Wqkv = (const float*)d_in[1];
  const float* temp = (const float*)d_in[2];
  const float* Wproj = (const float*)d_in[3];
  const float* bproj = (const float*)d_in[4];
  float* out = (float*)d_out;

  char* ws = (char*)d_ws;
  u16* Xh = (u16*)ws;                       // 50,331,648 B
  u16* XhT = (u16*)(ws + 50331648);         // 50,331,648 B
  u16* Wt = (u16*)(ws + 100663296);         // 2,359,296 B
  u16* Wvh = (u16*)(ws + 103022592);        // 1,179,648 B
  u16* XtXp = (u16*)(ws + 104202240);       // 32 z x 21 tiles x 16384 bf16
  u16* XtXbf = (u16*)(ws + 141950976);      // 8 x 589824 bf16
  u16* T = (u16*)(ws + 151388160);          // 8 x 1536 x 768 bf16
  u16* WeffT = (u16*)(ws + 151388160);      // alias: T dead after k_score
  u16* WcompT = (u16*)(ws + 160825344);
  float* Aattn = (float*)(ws + 170262528);  // 64 x 9216 f32
  // total ws use: 172,621,824 B

  // 1. x -> Xh + XhT
  k_cvtT<<<dim3(64, 12, 8), 256, 0, stream>>>(x, Xh, XhT);
  // 2. Wqkv -> Wt + Wvh
  k_wt<<<dim3(72, 24), 256, 0, stream>>>(Wqkv, Wt, Wvh);
  // 3. XtX triangle partials: per (b,s), 21 tile-pairs
  k_gemm<0, 1><<<dim3(21, 1, 32), 256, 0, stream>>>(
      XhT, XhT, (void*)XtXp, nullptr, 1024, 4096, 4096, 0,
      3145728L, 3145728L, 344064L, 4, 1024L);
  // 4. reduce + mirror -> XtXbf (full square)
  k_red<<<dim3(36, 8), 256, 0, stream>>>(XtXp, XtXbf);
  // 5. T[b] = Wt @ XtXbf_b (symmetric -> Bt=XtX)
  k_gemm<0, 0><<<dim3(6, 12, 8), 256, 0, stream>>>(
      Wt, XtXbf, (void*)T, nullptr, 768, 768, 768, 768,
      0L, 589824L, 1179648L, 1, 0L);
  // 6. scores + softmax -> Aattn
  k_score<<<dim3(8, 8), 256, 0, stream>>>(T, Wt, temp, Aattn);
  // 7. WeffT = blockdiag(A)^T @ Wproj
  k_weff<<<dim3(6, 8, 8), 256, 0, stream>>>(Aattn, Wproj, WeffT);
  // 8. WcompT[b][j][k] = sum_e WeffT[b][j][e] * Wvh[k][e]
  k_gemm<0, 0><<<dim3(6, 6, 8), 256, 0, stream>>>(
      WeffT, Wvh, (void*)WcompT, nullptr, 768, 768, 768, 768,
      589824L, 0L, 589824L, 1, 0L);
  // 9. out = Xh_b @ Wcomp_b + bproj (f32 out)
  k_gemm<1, 0><<<dim3(6, 32, 8), 256, 0, stream>>>(
      Xh, WcompT, out, bproj, 768, 768, 768, 768,
      3145728L, 589824L, 3145728L, 1, 0L);
}